// Round 1
// baseline (13711.829 us; speedup 1.0000x reference)
//
#include <hip/hip_runtime.h>
#include <cstddef>

#define NND 50000
#define NED 400000
#define HD 128
#define NSTEP 3

constexpr int TR = 8;  // rows per block; 128 threads = 8 rows x 16 channel-groups x 8 ch

__device__ __forceinline__ void fma8(float (&acc)[8], float m, const float4 w0, const float4 w1) {
    acc[0] += m * w0.x; acc[1] += m * w0.y; acc[2] += m * w0.z; acc[3] += m * w0.w;
    acc[4] += m * w1.x; acc[5] += m * w1.y; acc[6] += m * w1.z; acc[7] += m * w1.w;
}

__device__ __forceinline__ void bias_init(float (&acc)[8], const float* __restrict__ b, int jg) {
    const float4 b0 = ((const float4*)b)[jg * 2];
    const float4 b1 = ((const float4*)b)[jg * 2 + 1];
    acc[0] = b0.x; acc[1] = b0.y; acc[2] = b0.z; acc[3] = b0.w;
    acc[4] = b1.x; acc[5] = b1.y; acc[6] = b1.z; acc[7] = b1.w;
}

// Dense layer: acc[8] = b[j0..j0+7] + sum_k in_row[k] * W[k][j0..j0+7]
// in_row points into LDS (row base, padded stride handled by caller).
template <int K>
__device__ __forceinline__ void layer_lds(const float* in_row,
                                          const float* __restrict__ W,
                                          const float* __restrict__ b,
                                          int jg, float (&acc)[8]) {
    bias_init(acc, b, jg);
    const float4* Wv = (const float4*)W + jg * 2;
    #pragma unroll 2
    for (int k = 0; k < K; k += 4) {
        float4 mv = *(const float4*)(in_row + k);
        #pragma unroll
        for (int kk = 0; kk < 4; kk++) {
            float m = (&mv.x)[kk];
            float4 w0 = Wv[(k + kk) * (HD / 4)];
            float4 w1 = Wv[(k + kk) * (HD / 4) + 1];
            fma8(acc, m, w0, w1);
        }
    }
}

__device__ __forceinline__ void relu_store(float* out_row, int jg, const float (&acc)[8]) {
    float4 a = make_float4(fmaxf(acc[0], 0.f), fmaxf(acc[1], 0.f), fmaxf(acc[2], 0.f), fmaxf(acc[3], 0.f));
    float4 b = make_float4(fmaxf(acc[4], 0.f), fmaxf(acc[5], 0.f), fmaxf(acc[6], 0.f), fmaxf(acc[7], 0.f));
    ((float4*)out_row)[jg * 2] = a;
    ((float4*)out_row)[jg * 2 + 1] = b;
}

// ---------------- encoder (K = 4 or 3) ----------------
__global__ __launch_bounds__(128) void enc_kernel(
    const float* __restrict__ in, int K,
    const float* __restrict__ W1, const float* __restrict__ b1,
    const float* __restrict__ W2, const float* __restrict__ b2,
    const float* __restrict__ W3, const float* __restrict__ b3,
    float* __restrict__ out) {
    __shared__ __align__(16) float in_t[TR][4];
    __shared__ __align__(16) float t1[TR][HD + 4];
    __shared__ __align__(16) float t2[TR][HD + 4];
    const int tid = threadIdx.x;
    const int r = tid >> 4, jg = tid & 15;
    const int row = blockIdx.x * TR + r;

    if (jg < K) in_t[r][jg] = in[(size_t)row * K + jg];
    __syncthreads();

    float acc[8];
    // layer 1 (tiny K)
    bias_init(acc, b1, jg);
    {
        const float4* Wv = (const float4*)W1 + jg * 2;
        for (int k = 0; k < K; k++) {
            float m = in_t[r][k];
            float4 w0 = Wv[k * (HD / 4)];
            float4 w1 = Wv[k * (HD / 4) + 1];
            fma8(acc, m, w0, w1);
        }
    }
    relu_store(&t1[r][0], jg, acc);
    __syncthreads();
    layer_lds<HD>(&t1[r][0], W2, b2, jg, acc);
    relu_store(&t2[r][0], jg, acc);
    __syncthreads();
    layer_lds<HD>(&t2[r][0], W3, b3, jg, acc);
    float4* ov = (float4*)(out + (size_t)row * HD + jg * 8);
    ov[0] = make_float4(acc[0], acc[1], acc[2], acc[3]);
    ov[1] = make_float4(acc[4], acc[5], acc[6], acc[7]);
}

// ---------------- edge step: gather -> MLP(3H,H,H) -> residual -> scatter-sum ----------------
__global__ __launch_bounds__(128) void edge_step_kernel(
    const float* __restrict__ h, float* __restrict__ e,
    const int* __restrict__ eidx,
    const float* __restrict__ W1, const float* __restrict__ b1,
    const float* __restrict__ W2, const float* __restrict__ b2,
    const float* __restrict__ W3, const float* __restrict__ b3,
    float* __restrict__ agg) {
    __shared__ __align__(16) float m_t[TR][3 * HD + 4];
    __shared__ __align__(16) float t1[TR][HD + 4];
    __shared__ __align__(16) float t2[TR][HD + 4];
    const int tid = threadIdx.x;
    const int r = tid >> 4, jg = tid & 15;
    const int row = blockIdx.x * TR + r;
    const int s = eidx[row];
    const int d = eidx[NED + row];
    {
        const float4* hs = (const float4*)(h + (size_t)s * HD);
        const float4* hd = (const float4*)(h + (size_t)d * HD);
        const float4* ev = (const float4*)(e + (size_t)row * HD);
        float4* m0 = (float4*)&m_t[r][0];
        float4* m1 = (float4*)&m_t[r][HD];
        float4* m2 = (float4*)&m_t[r][2 * HD];
        m0[jg * 2] = hs[jg * 2]; m0[jg * 2 + 1] = hs[jg * 2 + 1];
        m1[jg * 2] = hd[jg * 2]; m1[jg * 2 + 1] = hd[jg * 2 + 1];
        m2[jg * 2] = ev[jg * 2]; m2[jg * 2 + 1] = ev[jg * 2 + 1];
    }
    __syncthreads();

    float acc[8];
    layer_lds<3 * HD>(&m_t[r][0], W1, b1, jg, acc);
    relu_store(&t1[r][0], jg, acc);
    __syncthreads();
    layer_lds<HD>(&t1[r][0], W2, b2, jg, acc);
    relu_store(&t2[r][0], jg, acc);
    __syncthreads();
    layer_lds<HD>(&t2[r][0], W3, b3, jg, acc);

    // residual with old e (still in m_t), write back, scatter into agg
    float4 e0 = *(const float4*)&m_t[r][2 * HD + jg * 8];
    float4 e1 = *(const float4*)&m_t[r][2 * HD + jg * 8 + 4];
    float o[8] = {e0.x + acc[0], e0.y + acc[1], e0.z + acc[2], e0.w + acc[3],
                  e1.x + acc[4], e1.y + acc[5], e1.z + acc[6], e1.w + acc[7]};
    float4* eo = (float4*)(e + (size_t)row * HD + jg * 8);
    eo[0] = make_float4(o[0], o[1], o[2], o[3]);
    eo[1] = make_float4(o[4], o[5], o[6], o[7]);
    float* ag = agg + (size_t)d * HD + jg * 8;
    #pragma unroll
    for (int c = 0; c < 8; c++) atomicAdd(ag + c, o[c]);
}

// ---------------- node step: MLP(2H,H,H) with residual ----------------
__global__ __launch_bounds__(128) void node_step_kernel(
    float* __restrict__ h, const float* __restrict__ agg,
    const float* __restrict__ W1, const float* __restrict__ b1,
    const float* __restrict__ W2, const float* __restrict__ b2,
    const float* __restrict__ W3, const float* __restrict__ b3) {
    __shared__ __align__(16) float m_t[TR][2 * HD + 4];
    __shared__ __align__(16) float t1[TR][HD + 4];
    __shared__ __align__(16) float t2[TR][HD + 4];
    const int tid = threadIdx.x;
    const int r = tid >> 4, jg = tid & 15;
    const int row = blockIdx.x * TR + r;
    {
        const float4* hv = (const float4*)(h + (size_t)row * HD);
        const float4* av = (const float4*)(agg + (size_t)row * HD);
        float4* m0 = (float4*)&m_t[r][0];
        float4* m1 = (float4*)&m_t[r][HD];
        m0[jg * 2] = hv[jg * 2]; m0[jg * 2 + 1] = hv[jg * 2 + 1];
        m1[jg * 2] = av[jg * 2]; m1[jg * 2 + 1] = av[jg * 2 + 1];
    }
    __syncthreads();

    float acc[8];
    layer_lds<2 * HD>(&m_t[r][0], W1, b1, jg, acc);
    relu_store(&t1[r][0], jg, acc);
    __syncthreads();
    layer_lds<HD>(&t1[r][0], W2, b2, jg, acc);
    relu_store(&t2[r][0], jg, acc);
    __syncthreads();
    layer_lds<HD>(&t2[r][0], W3, b3, jg, acc);

    float4 h0 = *(const float4*)&m_t[r][jg * 8];
    float4 h1 = *(const float4*)&m_t[r][jg * 8 + 4];
    float4* ho = (float4*)(h + (size_t)row * HD + jg * 8);
    ho[0] = make_float4(h0.x + acc[0], h0.y + acc[1], h0.z + acc[2], h0.w + acc[3]);
    ho[1] = make_float4(h1.x + acc[4], h1.y + acc[5], h1.z + acc[6], h1.w + acc[7]);
}

// ---------------- decoder: MLP(H,H,OUT=2) ----------------
__global__ __launch_bounds__(128) void dec_kernel(
    const float* __restrict__ h,
    const float* __restrict__ W1, const float* __restrict__ b1,
    const float* __restrict__ W2, const float* __restrict__ b2,
    const float* __restrict__ W3, const float* __restrict__ b3,
    float* __restrict__ out) {
    __shared__ __align__(16) float in_t[TR][HD + 4];
    __shared__ __align__(16) float t1[TR][HD + 4];
    __shared__ __align__(16) float t2[TR][HD + 4];
    const int tid = threadIdx.x;
    const int r = tid >> 4, jg = tid & 15;
    const int row = blockIdx.x * TR + r;
    {
        const float4* hv = (const float4*)(h + (size_t)row * HD);
        float4* m0 = (float4*)&in_t[r][0];
        m0[jg * 2] = hv[jg * 2]; m0[jg * 2 + 1] = hv[jg * 2 + 1];
    }
    __syncthreads();

    float acc[8];
    layer_lds<HD>(&in_t[r][0], W1, b1, jg, acc);
    relu_store(&t1[r][0], jg, acc);
    __syncthreads();
    layer_lds<HD>(&t1[r][0], W2, b2, jg, acc);
    relu_store(&t2[r][0], jg, acc);
    __syncthreads();

    if (tid < TR * 2) {
        int rr = tid >> 1, o = tid & 1;
        float a = b3[o];
        for (int k = 0; k < HD; k++) a += t2[rr][k] * W3[k * 2 + o];
        out[(size_t)(blockIdx.x * TR + rr) * 2 + o] = a;
    }
}

extern "C" void kernel_launch(void* const* d_in, const int* in_sizes, int n_in,
                              void* d_out, int out_size, void* d_ws, size_t ws_size,
                              hipStream_t stream) {
    (void)in_sizes; (void)n_in; (void)out_size; (void)ws_size;
    const float* x    = (const float*)d_in[0];
    const float* eatt = (const float*)d_in[1];
    const int*   eidx = (const int*)d_in[2];
    const float *neW1 = (const float*)d_in[3],  *neb1 = (const float*)d_in[4];
    const float *neW2 = (const float*)d_in[5],  *neb2 = (const float*)d_in[6];
    const float *neW3 = (const float*)d_in[7],  *neb3 = (const float*)d_in[8];
    const float *eeW1 = (const float*)d_in[9],  *eeb1 = (const float*)d_in[10];
    const float *eeW2 = (const float*)d_in[11], *eeb2 = (const float*)d_in[12];
    const float *eeW3 = (const float*)d_in[13], *eeb3 = (const float*)d_in[14];
    const float *peW1 = (const float*)d_in[15], *peb1 = (const float*)d_in[16];
    const float *peW2 = (const float*)d_in[17], *peb2 = (const float*)d_in[18];
    const float *peW3 = (const float*)d_in[19], *peb3 = (const float*)d_in[20];
    const float *pnW1 = (const float*)d_in[21], *pnb1 = (const float*)d_in[22];
    const float *pnW2 = (const float*)d_in[23], *pnb2 = (const float*)d_in[24];
    const float *pnW3 = (const float*)d_in[25], *pnb3 = (const float*)d_in[26];
    const float *ndW1 = (const float*)d_in[27], *ndb1 = (const float*)d_in[28];
    const float *ndW2 = (const float*)d_in[29], *ndb2 = (const float*)d_in[30];
    const float *ndW3 = (const float*)d_in[31], *ndb3 = (const float*)d_in[32];

    float* ws  = (float*)d_ws;
    float* h   = ws;                           // [NND, HD]
    float* e   = h + (size_t)NND * HD;         // [NED, HD]
    float* agg = e + (size_t)NED * HD;         // [NND, HD]

    enc_kernel<<<NND / TR, 128, 0, stream>>>(x, 4, neW1, neb1, neW2, neb2, neW3, neb3, h);
    enc_kernel<<<NED / TR, 128, 0, stream>>>(eatt, 3, eeW1, eeb1, eeW2, eeb2, eeW3, eeb3, e);

    for (int t = 0; t < NSTEP; t++) {
        hipMemsetAsync(agg, 0, (size_t)NND * HD * sizeof(float), stream);
        edge_step_kernel<<<NED / TR, 128, 0, stream>>>(
            h, e, eidx,
            peW1 + (size_t)t * 3 * HD * HD, peb1 + (size_t)t * HD,
            peW2 + (size_t)t * HD * HD,     peb2 + (size_t)t * HD,
            peW3 + (size_t)t * HD * HD,     peb3 + (size_t)t * HD,
            agg);
        node_step_kernel<<<NND / TR, 128, 0, stream>>>(
            h, agg,
            pnW1 + (size_t)t * 2 * HD * HD, pnb1 + (size_t)t * HD,
            pnW2 + (size_t)t * HD * HD,     pnb2 + (size_t)t * HD,
            pnW3 + (size_t)t * HD * HD,     pnb3 + (size_t)t * HD);
    }
    dec_kernel<<<NND / TR, 128, 0, stream>>>(h, ndW1, ndb1, ndW2, ndb2, ndW3, ndb3, (float*)d_out);
}

// Round 2
// 9000.620 us; speedup vs baseline: 1.5234x; 1.5234x over previous
//
#include <hip/hip_runtime.h>
#include <cstddef>
#include <cstdint>

#define NND 50000
#define NNDP 50016   // padded to multiple of 32
#define NED 400000
#define HD 128
#define NSTEP 3

using u16 = unsigned short;
typedef __attribute__((ext_vector_type(8))) short bf16x8;
typedef __attribute__((ext_vector_type(4))) float f32x4;

__device__ __forceinline__ u16 f2b(float f) {
    union { float f; unsigned u; } v; v.f = f;
    unsigned r = v.u + 0x7FFFu + ((v.u >> 16) & 1u);
    return (u16)(r >> 16);
}
__device__ __forceinline__ float b2f(u16 u) {
    union { unsigned u; float f; } v; v.u = ((unsigned)u) << 16;
    return v.f;
}

// One dense layer via MFMA. Block = 256 thr = 4 waves; wave (wr,wc) computes
// rows [wr*16, wr*16+16) x cols [wc*64, wc*64+64) of the 32x128 output tile.
// A is an LDS bf16 tile [32][strideA]; Wt is global bf16 B^T layout [128][Kpad].
template <int K>
__device__ __forceinline__ void gemm_layer(const u16* Ab, int strideA,
                                           const u16* __restrict__ Wt, int Kpad,
                                           int wr, int wc, int lane, f32x4 (&acc)[4]) {
    const int cl = lane & 15;
    const int kl = (lane >> 4) * 8;
    const u16* arow = Ab + (wr * 16 + cl) * strideA + kl;
    const u16* wbase = Wt + (size_t)(wc * 64 + cl) * Kpad + kl;
    #pragma unroll
    for (int i = 0; i < 4; i++) acc[i] = (f32x4)(0.0f);
    #pragma unroll 4
    for (int k0 = 0; k0 < K; k0 += 32) {
        bf16x8 a  = *(const bf16x8*)(arow + k0);
        bf16x8 b0 = *(const bf16x8*)(wbase + k0);
        bf16x8 b1 = *(const bf16x8*)(wbase + 16 * Kpad + k0);
        bf16x8 b2 = *(const bf16x8*)(wbase + 32 * Kpad + k0);
        bf16x8 b3 = *(const bf16x8*)(wbase + 48 * Kpad + k0);
        acc[0] = __builtin_amdgcn_mfma_f32_16x16x32_bf16(a, b0, acc[0], 0, 0, 0);
        acc[1] = __builtin_amdgcn_mfma_f32_16x16x32_bf16(a, b1, acc[1], 0, 0, 0);
        acc[2] = __builtin_amdgcn_mfma_f32_16x16x32_bf16(a, b2, acc[2], 0, 0, 0);
        acc[3] = __builtin_amdgcn_mfma_f32_16x16x32_bf16(a, b3, acc[3], 0, 0, 0);
    }
}

// C/D layout (m89-verified): col = lane&15, row = (lane>>4)*4 + reg.
template <bool RELU>
__device__ __forceinline__ void store_tile_bf16(u16* T, int strideT,
        int wr, int wc, int lane, const f32x4 (&acc)[4], const float* __restrict__ bias) {
    const int cl = lane & 15;
    const int r0 = wr * 16 + (lane >> 4) * 4;
    #pragma unroll
    for (int ct = 0; ct < 4; ct++) {
        int col = wc * 64 + ct * 16 + cl;
        float bv = bias[col];
        #pragma unroll
        for (int i = 0; i < 4; i++) {
            float v = acc[ct][i] + bv;
            if (RELU) v = fmaxf(v, 0.0f);
            T[(r0 + i) * strideT + col] = f2b(v);
        }
    }
}

// ---------------- weight prep: fp32 [K][N] -> bf16 [N][Kpad] (zero-padded) ----------------
__global__ void wprep(const float* __restrict__ src, u16* __restrict__ dst,
                      int K, int N, int Kpad) {
    int idx = blockIdx.x * 256 + threadIdx.x;
    if (idx >= N * Kpad) return;
    int n = idx / Kpad, k = idx - n * Kpad;
    float v = (k < K) ? src[(size_t)k * N + n] : 0.0f;
    dst[idx] = f2b(v);
}

// ---------------- encoder: fp32 [rows][Kin] -> MLP(Kin,H,H,H) -> bf16 out ----------------
__global__ __launch_bounds__(256, 3) void enc_mfma(
    const float* __restrict__ in, int Kin, int nrows,
    const u16* __restrict__ W1t, const float* __restrict__ b1,
    const u16* __restrict__ W2t, const float* __restrict__ b2,
    const u16* __restrict__ W3t, const float* __restrict__ b3,
    u16* __restrict__ out) {
    __shared__ u16 A[32 * 40];
    __shared__ u16 t1[32 * 136];
    __shared__ u16 t2[32 * 136];
    const int tid = threadIdx.x;
    const int lane = tid & 63, w = tid >> 6, wr = w >> 1, wc = w & 1;
    const int row0 = blockIdx.x * 32;
    if (tid < 32) {
        int grow = row0 + tid;
        #pragma unroll
        for (int k = 0; k < 32; k++) {
            float v = 0.0f;
            if (k < Kin && grow < nrows) v = in[(size_t)grow * Kin + k];
            A[tid * 40 + k] = f2b(v);
        }
    }
    __syncthreads();
    f32x4 acc[4];
    gemm_layer<32>(A, 40, W1t, 32, wr, wc, lane, acc);
    store_tile_bf16<true>(t1, 136, wr, wc, lane, acc, b1);
    __syncthreads();
    gemm_layer<128>(t1, 136, W2t, 128, wr, wc, lane, acc);
    store_tile_bf16<true>(t2, 136, wr, wc, lane, acc, b2);
    __syncthreads();
    gemm_layer<128>(t2, 136, W3t, 128, wr, wc, lane, acc);
    store_tile_bf16<false>(t1, 136, wr, wc, lane, acc, b3);
    __syncthreads();
    const int r = tid >> 3, sgi = tid & 7;
    const int grow = row0 + r;
    if (grow < nrows) {
        float4* dst = (float4*)(out + (size_t)grow * HD);
        dst[sgi]     = *(const float4*)(t1 + r * 136 + sgi * 8);
        dst[8 + sgi] = *(const float4*)(t1 + r * 136 + 64 + sgi * 8);
    }
}

// ---------------- edge step: gather -> MLP(3H,H,H) -> +e -> store e, scatter agg ----------------
__global__ __launch_bounds__(256, 3) void edge_mfma(
    const u16* __restrict__ h, u16* __restrict__ e,
    const int* __restrict__ eidx,
    const u16* __restrict__ W1t, const float* __restrict__ b1,
    const u16* __restrict__ W2t, const float* __restrict__ b2,
    const u16* __restrict__ W3t, const float* __restrict__ b3,
    float* __restrict__ agg) {
    __shared__ u16 A[32 * 392];
    __shared__ u16 t1[32 * 136];
    __shared__ u16 t2[32 * 136];
    __shared__ int dsts[32];
    const int tid = threadIdx.x;
    const int lane = tid & 63, w = tid >> 6, wr = w >> 1, wc = w & 1;
    const int row0 = blockIdx.x * 32;
    {
        const int r = tid >> 3, sgi = tid & 7;
        const int grow = row0 + r;
        const int s = eidx[grow];
        const int d = eidx[NED + grow];
        if (sgi == 0) dsts[r] = d;
        const float4* hs  = (const float4*)(h + (size_t)s * HD);
        const float4* hdv = (const float4*)(h + (size_t)d * HD);
        const float4* ev  = (const float4*)(e + (size_t)grow * HD);
        float4* Ar = (float4*)(A + r * 392);
        Ar[sgi]      = hs[sgi];   Ar[8 + sgi]  = hs[8 + sgi];
        Ar[16 + sgi] = hdv[sgi];  Ar[24 + sgi] = hdv[8 + sgi];
        Ar[32 + sgi] = ev[sgi];   Ar[40 + sgi] = ev[8 + sgi];
    }
    __syncthreads();
    f32x4 acc[4];
    gemm_layer<384>(A, 392, W1t, 384, wr, wc, lane, acc);
    store_tile_bf16<true>(t1, 136, wr, wc, lane, acc, b1);
    __syncthreads();
    gemm_layer<128>(t1, 136, W2t, 128, wr, wc, lane, acc);
    store_tile_bf16<true>(t2, 136, wr, wc, lane, acc, b2);
    __syncthreads();
    gemm_layer<128>(t2, 136, W3t, 128, wr, wc, lane, acc);
    {   // residual with old e (A cols 256..383), write bf16 result into t1
        const int cl = lane & 15;
        const int r0 = wr * 16 + (lane >> 4) * 4;
        #pragma unroll
        for (int ct = 0; ct < 4; ct++) {
            int col = wc * 64 + ct * 16 + cl;
            float bv = b3[col];
            #pragma unroll
            for (int i = 0; i < 4; i++) {
                float old = b2f(A[(r0 + i) * 392 + 256 + col]);
                t1[(r0 + i) * 136 + col] = f2b(old + acc[ct][i] + bv);
            }
        }
    }
    __syncthreads();
    {
        const int r = tid >> 3, sgi = tid & 7;
        const int grow = row0 + r;
        float4* eo = (float4*)(e + (size_t)grow * HD);
        eo[sgi]     = *(const float4*)(t1 + r * 136 + sgi * 8);
        eo[8 + sgi] = *(const float4*)(t1 + r * 136 + 64 + sgi * 8);
        float* ag = agg + (size_t)dsts[r] * HD + sgi * 16;
        #pragma unroll
        for (int c = 0; c < 16; c++)
            atomicAdd(ag + c, b2f(t1[r * 136 + sgi * 16 + c]));
    }
}

// ---------------- node step: [h|agg] -> MLP(2H,H,H) -> +h -> store h ----------------
__global__ __launch_bounds__(256, 3) void node_mfma(
    u16* __restrict__ h, const float* __restrict__ agg,
    const u16* __restrict__ W1t, const float* __restrict__ b1,
    const u16* __restrict__ W2t, const float* __restrict__ b2,
    const u16* __restrict__ W3t, const float* __restrict__ b3) {
    __shared__ u16 A[32 * 264];
    __shared__ u16 t1[32 * 136];
    __shared__ u16 t2[32 * 136];
    const int tid = threadIdx.x;
    const int lane = tid & 63, w = tid >> 6, wr = w >> 1, wc = w & 1;
    const int row0 = blockIdx.x * 32;
    {
        const int r = tid >> 3, sgi = tid & 7;
        const int grow = row0 + r;  // < NNDP (buffers padded)
        const float4* hv = (const float4*)(h + (size_t)grow * HD);
        float4* Ar = (float4*)(A + r * 264);
        Ar[sgi]     = hv[sgi];
        Ar[8 + sgi] = hv[8 + sgi];
        const float4* av = (const float4*)(agg + (size_t)grow * HD) + sgi * 4;
        uint2* Ad = (uint2*)(A + r * 264 + 128 + sgi * 16);
        #pragma unroll
        for (int j = 0; j < 4; j++) {
            float4 f = av[j];
            uint2 pk;
            pk.x = (unsigned)f2b(f.x) | ((unsigned)f2b(f.y) << 16);
            pk.y = (unsigned)f2b(f.z) | ((unsigned)f2b(f.w) << 16);
            Ad[j] = pk;
        }
    }
    __syncthreads();
    f32x4 acc[4];
    gemm_layer<256>(A, 264, W1t, 256, wr, wc, lane, acc);
    store_tile_bf16<true>(t1, 136, wr, wc, lane, acc, b1);
    __syncthreads();
    gemm_layer<128>(t1, 136, W2t, 128, wr, wc, lane, acc);
    store_tile_bf16<true>(t2, 136, wr, wc, lane, acc, b2);
    __syncthreads();
    gemm_layer<128>(t2, 136, W3t, 128, wr, wc, lane, acc);
    {   // residual with old h (A cols 0..127)
        const int cl = lane & 15;
        const int r0 = wr * 16 + (lane >> 4) * 4;
        #pragma unroll
        for (int ct = 0; ct < 4; ct++) {
            int col = wc * 64 + ct * 16 + cl;
            float bv = b3[col];
            #pragma unroll
            for (int i = 0; i < 4; i++) {
                float old = b2f(A[(r0 + i) * 264 + col]);
                t1[(r0 + i) * 136 + col] = f2b(old + acc[ct][i] + bv);
            }
        }
    }
    __syncthreads();
    {
        const int r = tid >> 3, sgi = tid & 7;
        const int grow = row0 + r;
        float4* ho = (float4*)(h + (size_t)grow * HD);
        ho[sgi]     = *(const float4*)(t1 + r * 136 + sgi * 8);
        ho[8 + sgi] = *(const float4*)(t1 + r * 136 + 64 + sgi * 8);
    }
}

// ---------------- decoder: h -> MLP(H,H,OUT=2) fp32 out ----------------
__global__ __launch_bounds__(256, 3) void dec_mfma(
    const u16* __restrict__ h,
    const u16* __restrict__ W1t, const float* __restrict__ b1,
    const u16* __restrict__ W2t, const float* __restrict__ b2,
    const float* __restrict__ W3, const float* __restrict__ b3,
    float* __restrict__ out) {
    __shared__ u16 A[32 * 136];
    __shared__ u16 t1[32 * 136];
    __shared__ u16 t2[32 * 136];
    const int tid = threadIdx.x;
    const int lane = tid & 63, w = tid >> 6, wr = w >> 1, wc = w & 1;
    const int row0 = blockIdx.x * 32;
    {
        const int r = tid >> 3, sgi = tid & 7;
        const int grow = row0 + r;  // < NNDP
        const float4* hv = (const float4*)(h + (size_t)grow * HD);
        float4* Ar = (float4*)(A + r * 136);
        Ar[sgi]     = hv[sgi];
        Ar[8 + sgi] = hv[8 + sgi];
    }
    __syncthreads();
    f32x4 acc[4];
    gemm_layer<128>(A, 136, W1t, 128, wr, wc, lane, acc);
    store_tile_bf16<true>(t1, 136, wr, wc, lane, acc, b1);
    __syncthreads();
    gemm_layer<128>(t1, 136, W2t, 128, wr, wc, lane, acc);
    store_tile_bf16<true>(t2, 136, wr, wc, lane, acc, b2);
    __syncthreads();
    if (tid < 64) {
        const int rr = tid >> 1, o = tid & 1;
        const int grow = row0 + rr;
        if (grow < NND) {
            float a = b3[o];
            for (int k = 0; k < HD; k++) a += b2f(t2[rr * 136 + k]) * W3[k * 2 + o];
            out[(size_t)grow * 2 + o] = a;
        }
    }
}

extern "C" void kernel_launch(void* const* d_in, const int* in_sizes, int n_in,
                              void* d_out, int out_size, void* d_ws, size_t ws_size,
                              hipStream_t stream) {
    (void)in_sizes; (void)n_in; (void)out_size; (void)ws_size;
    const float* x    = (const float*)d_in[0];
    const float* eatt = (const float*)d_in[1];
    const int*   eidx = (const int*)d_in[2];
    const float *neW1 = (const float*)d_in[3],  *neb1 = (const float*)d_in[4];
    const float *neW2 = (const float*)d_in[5],  *neb2 = (const float*)d_in[6];
    const float *neW3 = (const float*)d_in[7],  *neb3 = (const float*)d_in[8];
    const float *eeW1 = (const float*)d_in[9],  *eeb1 = (const float*)d_in[10];
    const float *eeW2 = (const float*)d_in[11], *eeb2 = (const float*)d_in[12];
    const float *eeW3 = (const float*)d_in[13], *eeb3 = (const float*)d_in[14];
    const float *peW1 = (const float*)d_in[15], *peb1 = (const float*)d_in[16];
    const float *peW2 = (const float*)d_in[17], *peb2 = (const float*)d_in[18];
    const float *peW3 = (const float*)d_in[19], *peb3 = (const float*)d_in[20];
    const float *pnW1 = (const float*)d_in[21], *pnb1 = (const float*)d_in[22];
    const float *pnW2 = (const float*)d_in[23], *pnb2 = (const float*)d_in[24];
    const float *pnW3 = (const float*)d_in[25], *pnb3 = (const float*)d_in[26];
    const float *ndW1 = (const float*)d_in[27], *ndb1 = (const float*)d_in[28];
    const float *ndW2 = (const float*)d_in[29], *ndb2 = (const float*)d_in[30];
    const float *ndW3 = (const float*)d_in[31], *ndb3 = (const float*)d_in[32];

    char* ws = (char*)d_ws;
    u16*   h   = (u16*)ws;                                   // [NNDP][HD] bf16
    u16*   e   = (u16*)(ws + 12804096);                      // [NED][HD] bf16
    float* agg = (float*)(ws + 12804096 + 102400000);        // [NNDP][HD] f32
    u16*   wts = (u16*)(ws + 12804096 + 102400000 + 25608192);

    // weight table (bf16, transposed [N][Kpad])
    u16* p = wts;
    u16 *neW1t = p; p += 128 * 32;
    u16 *neW2t = p; p += 128 * 128;
    u16 *neW3t = p; p += 128 * 128;
    u16 *eeW1t = p; p += 128 * 32;
    u16 *eeW2t = p; p += 128 * 128;
    u16 *eeW3t = p; p += 128 * 128;
    u16 *peW1t[NSTEP], *peW2t[NSTEP], *peW3t[NSTEP];
    u16 *pnW1t[NSTEP], *pnW2t[NSTEP], *pnW3t[NSTEP];
    for (int t = 0; t < NSTEP; t++) {
        peW1t[t] = p; p += 128 * 384;
        peW2t[t] = p; p += 128 * 128;
        peW3t[t] = p; p += 128 * 128;
    }
    for (int t = 0; t < NSTEP; t++) {
        pnW1t[t] = p; p += 128 * 256;
        pnW2t[t] = p; p += 128 * 128;
        pnW3t[t] = p; p += 128 * 128;
    }
    u16 *ndW1t = p; p += 128 * 128;
    u16 *ndW2t = p; p += 128 * 128;

    auto WP = [&](const float* s, u16* d, int K, int N, int Kp) {
        int tot = N * Kp;
        wprep<<<(tot + 255) / 256, 256, 0, stream>>>(s, d, K, N, Kp);
    };
    WP(neW1, neW1t, 4, 128, 32);
    WP(neW2, neW2t, 128, 128, 128);
    WP(neW3, neW3t, 128, 128, 128);
    WP(eeW1, eeW1t, 3, 128, 32);
    WP(eeW2, eeW2t, 128, 128, 128);
    WP(eeW3, eeW3t, 128, 128, 128);
    for (int t = 0; t < NSTEP; t++) {
        WP(peW1 + (size_t)t * 384 * 128, peW1t[t], 384, 128, 384);
        WP(peW2 + (size_t)t * 128 * 128, peW2t[t], 128, 128, 128);
        WP(peW3 + (size_t)t * 128 * 128, peW3t[t], 128, 128, 128);
        WP(pnW1 + (size_t)t * 256 * 128, pnW1t[t], 256, 128, 256);
        WP(pnW2 + (size_t)t * 128 * 128, pnW2t[t], 128, 128, 128);
        WP(pnW3 + (size_t)t * 128 * 128, pnW3t[t], 128, 128, 128);
    }
    WP(ndW1, ndW1t, 128, 128, 128);
    WP(ndW2, ndW2t, 128, 128, 128);

    enc_mfma<<<NNDP / 32, 256, 0, stream>>>(x, 4, NND, neW1t, neb1, neW2t, neb2, neW3t, neb3, h);
    enc_mfma<<<NED / 32, 256, 0, stream>>>(eatt, 3, NED, eeW1t, eeb1, eeW2t, eeb2, eeW3t, eeb3, e);

    for (int t = 0; t < NSTEP; t++) {
        hipMemsetAsync(agg, 0, (size_t)NNDP * HD * sizeof(float), stream);
        edge_mfma<<<NED / 32, 256, 0, stream>>>(
            h, e, eidx,
            peW1t[t], peb1 + (size_t)t * HD,
            peW2t[t], peb2 + (size_t)t * HD,
            peW3t[t], peb3 + (size_t)t * HD,
            agg);
        node_mfma<<<NNDP / 32, 256, 0, stream>>>(
            h, agg,
            pnW1t[t], pnb1 + (size_t)t * HD,
            pnW2t[t], pnb2 + (size_t)t * HD,
            pnW3t[t], pnb3 + (size_t)t * HD);
    }
    dec_mfma<<<NNDP / 32, 256, 0, stream>>>(h, ndW1t, ndb1, ndW2t, ndb2, ndW3, ndb3, (float*)d_out);
}

// Round 3
// 8652.795 us; speedup vs baseline: 1.5847x; 1.0402x over previous
//
#include <hip/hip_runtime.h>
#include <cstddef>

#define NND 50000
#define NNDP 50016   // padded to multiple of 32
#define NED 400000
#define HD 128
#define NSTEP 3

using u16 = unsigned short;
typedef __attribute__((ext_vector_type(8))) short bf16x8;
typedef __attribute__((ext_vector_type(4))) float f32x4;

__device__ __forceinline__ u16 f2b(float f) {
    union { float f; unsigned u; } v; v.f = f;
    unsigned r = v.u + 0x7FFFu + ((v.u >> 16) & 1u);
    return (u16)(r >> 16);
}
__device__ __forceinline__ float b2f(u16 u) {
    union { unsigned u; float f; } v; v.u = ((unsigned)u) << 16;
    return v.f;
}

// 4 MFMAs covering 16 rows x 64 cols for one k0-chunk of 32.
// bp points at fragment-major weights: element ((n0*KC + k0)*64 + lane)*8.
__device__ __forceinline__ void mfma4(bf16x8 a, const u16* bp, int ctStride, f32x4 (&acc)[4]) {
    bf16x8 b0 = *(const bf16x8*)(bp);
    bf16x8 b1 = *(const bf16x8*)(bp + ctStride);
    bf16x8 b2 = *(const bf16x8*)(bp + 2 * ctStride);
    bf16x8 b3 = *(const bf16x8*)(bp + 3 * ctStride);
    acc[0] = __builtin_amdgcn_mfma_f32_16x16x32_bf16(a, b0, acc[0], 0, 0, 0);
    acc[1] = __builtin_amdgcn_mfma_f32_16x16x32_bf16(a, b1, acc[1], 0, 0, 0);
    acc[2] = __builtin_amdgcn_mfma_f32_16x16x32_bf16(a, b2, acc[2], 0, 0, 0);
    acc[3] = __builtin_amdgcn_mfma_f32_16x16x32_bf16(a, b3, acc[3], 0, 0, 0);
}

__device__ __forceinline__ void zero_acc(f32x4 (&acc)[4]) {
    #pragma unroll
    for (int i = 0; i < 4; i++) acc[i] = (f32x4)(0.0f);
}

// K=128 layer with A in LDS t-buffer (stride 136 u16), weights fragment-major (KC=4).
__device__ __forceinline__ void gemm_tb(const u16* tb, const u16* __restrict__ Wf,
                                        int wr, int wc, int lane, f32x4 (&acc)[4]) {
    const int cl = lane & 15, kl8 = (lane >> 4) * 8;
    const u16* ar = tb + (wr * 16 + cl) * 136 + kl8;
    const u16* bp = Wf + (size_t)(wc * 4 * 4) * 512 + lane * 8;
    #pragma unroll
    for (int k0 = 0; k0 < 4; k0++) {
        bf16x8 a = *(const bf16x8*)(ar + k0 * 32);
        mfma4(a, bp + k0 * 512, 4 * 512, acc);
    }
}

// C/D layout (m89-verified): col = lane&15, row = (lane>>4)*4 + reg.
template <bool RELU>
__device__ __forceinline__ void store_tile(u16* T, int wr, int wc, int lane,
                                           const f32x4 (&acc)[4], const float* __restrict__ bias) {
    const int cl = lane & 15;
    const int r0 = wr * 16 + (lane >> 4) * 4;
    #pragma unroll
    for (int ct = 0; ct < 4; ct++) {
        int col = wc * 64 + ct * 16 + cl;
        float bv = bias[col];
        #pragma unroll
        for (int i = 0; i < 4; i++) {
            float v = acc[ct][i] + bv;
            if (RELU) v = fmaxf(v, 0.0f);
            T[(r0 + i) * 136 + col] = f2b(v);
        }
    }
}

// ---------------- weight prep: fp32 [K][128] -> bf16 fragment-major ----------------
// dst index = ((n0*(Kp/32) + k0)*64 + lane)*8 + j ; lane: cl=lane&15 -> col, q=lane>>4 -> k-subgroup
__global__ void wprep_frag(const float* __restrict__ src, u16* __restrict__ dst, int K, int Kp) {
    int idx = blockIdx.x * 256 + threadIdx.x;
    if (idx >= 128 * Kp) return;
    int j = idx & 7, lane = (idx >> 3) & 63, rest = idx >> 9;
    int KC = Kp >> 5;
    int k0 = rest % KC, n0 = rest / KC;
    int n = n0 * 16 + (lane & 15);
    int k = k0 * 32 + (lane >> 4) * 8 + j;
    float v = (k < K) ? src[(size_t)k * 128 + n] : 0.0f;
    dst[idx] = f2b(v);
}

// ---------------- encoder: fp32 [rows][Kin] -> MLP(Kin,H,H,H) -> bf16 out ----------------
__global__ __launch_bounds__(256, 4) void enc_mfma(
    const float* __restrict__ in, int Kin, int nrows,
    const u16* __restrict__ W1f, const float* __restrict__ b1,
    const u16* __restrict__ W2f, const float* __restrict__ b2,
    const u16* __restrict__ W3f, const float* __restrict__ b3,
    u16* __restrict__ out) {
    __shared__ u16 tb[32 * 136];
    const int tid = threadIdx.x;
    const int lane = tid & 63, w = tid >> 6, wr = w >> 1, wc = w & 1;
    const int cl = lane & 15, kl8 = (lane >> 4) * 8;
    const int row0 = blockIdx.x * 32;
    const int grow = row0 + wr * 16 + cl;

    f32x4 acc[4];
    zero_acc(acc);
    bf16x8 a = {0, 0, 0, 0, 0, 0, 0, 0};
    if (kl8 == 0 && grow < nrows) {
        const float* xr = in + (size_t)grow * Kin;
        if (Kin == 4) {
            float4 v = *(const float4*)xr;
            a[0] = (short)f2b(v.x); a[1] = (short)f2b(v.y);
            a[2] = (short)f2b(v.z); a[3] = (short)f2b(v.w);
        } else {
            a[0] = (short)f2b(xr[0]); a[1] = (short)f2b(xr[1]); a[2] = (short)f2b(xr[2]);
        }
    }
    mfma4(a, W1f + (size_t)(wc * 4) * 512 + lane * 8, 512, acc);
    store_tile<true>(tb, wr, wc, lane, acc, b1);
    __syncthreads();
    zero_acc(acc);
    gemm_tb(tb, W2f, wr, wc, lane, acc);
    __syncthreads();
    store_tile<true>(tb, wr, wc, lane, acc, b2);
    __syncthreads();
    zero_acc(acc);
    gemm_tb(tb, W3f, wr, wc, lane, acc);
    __syncthreads();
    store_tile<false>(tb, wr, wc, lane, acc, b3);
    __syncthreads();
    const int r = tid >> 3, sgi = tid & 7;
    const int orow = row0 + r;
    if (orow < nrows) {
        float4* dst = (float4*)(out + (size_t)orow * HD);
        dst[sgi]     = *(const float4*)(tb + r * 136 + sgi * 8);
        dst[8 + sgi] = *(const float4*)(tb + r * 136 + 64 + sgi * 8);
    }
}

// ---------------- edge step: gather-frag -> MLP(3H,H,H) -> +e -> store e, scatter agg ----------------
__global__ __launch_bounds__(256, 4) void edge_mfma(
    const u16* __restrict__ h, u16* e,
    const int* __restrict__ eidx,
    const u16* __restrict__ W1f, const float* __restrict__ b1,
    const u16* __restrict__ W2f, const float* __restrict__ b2,
    const u16* __restrict__ W3f, const float* __restrict__ b3,
    float* __restrict__ agg) {
    __shared__ u16 tb[32 * 136];
    __shared__ int dsts[32];
    const int tid = threadIdx.x;
    const int lane = tid & 63, w = tid >> 6, wr = w >> 1, wc = w & 1;
    const int cl = lane & 15, kl8 = (lane >> 4) * 8;
    const int row0 = blockIdx.x * 32;
    const int myrow = row0 + wr * 16 + cl;
    if (tid < 32) dsts[tid] = eidx[NED + row0 + tid];
    const int s = eidx[myrow];
    const int d = eidx[NED + myrow];
    const u16* hs = h + (size_t)s * HD + kl8;
    const u16* hd = h + (size_t)d * HD + kl8;
    const u16* ep = e + (size_t)myrow * HD + kl8;

    f32x4 acc[4];
    zero_acc(acc);
    const int KC1 = 12;
    const u16* b1p = W1f + (size_t)(wc * 4 * KC1) * 512 + lane * 8;
    #pragma unroll
    for (int k0 = 0; k0 < 4; k0++) {
        bf16x8 a = *(const bf16x8*)(hs + k0 * 32);
        mfma4(a, b1p + k0 * 512, KC1 * 512, acc);
    }
    #pragma unroll
    for (int k0 = 0; k0 < 4; k0++) {
        bf16x8 a = *(const bf16x8*)(hd + k0 * 32);
        mfma4(a, b1p + (4 + k0) * 512, KC1 * 512, acc);
    }
    #pragma unroll
    for (int k0 = 0; k0 < 4; k0++) {
        bf16x8 a = *(const bf16x8*)(ep + k0 * 32);
        mfma4(a, b1p + (8 + k0) * 512, KC1 * 512, acc);
    }
    store_tile<true>(tb, wr, wc, lane, acc, b1);
    __syncthreads();
    zero_acc(acc);
    gemm_tb(tb, W2f, wr, wc, lane, acc);
    __syncthreads();
    store_tile<true>(tb, wr, wc, lane, acc, b2);
    __syncthreads();
    zero_acc(acc);
    gemm_tb(tb, W3f, wr, wc, lane, acc);
    __syncthreads();
    {   // residual with old e (global re-read, L2-hot) + bias, write to tb
        const int r0 = (lane >> 4) * 4;
        #pragma unroll
        for (int ct = 0; ct < 4; ct++) {
            int col = wc * 64 + ct * 16 + cl;
            float bv = b3[col];
            #pragma unroll
            for (int i = 0; i < 4; i++) {
                float old = b2f(e[(size_t)(row0 + wr * 16 + r0 + i) * HD + col]);
                tb[(wr * 16 + r0 + i) * 136 + col] = f2b(old + acc[ct][i] + bv);
            }
        }
    }
    __syncthreads();
    {
        const int r = tid >> 3, sgi = tid & 7;
        const int grow = row0 + r;
        float4* eo = (float4*)(e + (size_t)grow * HD);
        eo[sgi]     = *(const float4*)(tb + r * 136 + sgi * 8);
        eo[8 + sgi] = *(const float4*)(tb + r * 136 + 64 + sgi * 8);
        float* ag = agg + (size_t)dsts[r] * HD + sgi * 16;
        #pragma unroll
        for (int c = 0; c < 16; c++)
            atomicAdd(ag + c, b2f(tb[r * 136 + sgi * 16 + c]));
    }
}

// ---------------- node step: [h|agg] -> MLP(2H,H,H) -> +h -> store h ----------------
__global__ __launch_bounds__(256, 4) void node_mfma(
    u16* h, const float* __restrict__ agg,
    const u16* __restrict__ W1f, const float* __restrict__ b1,
    const u16* __restrict__ W2f, const float* __restrict__ b2,
    const u16* __restrict__ W3f, const float* __restrict__ b3) {
    __shared__ u16 tb[32 * 136];
    const int tid = threadIdx.x;
    const int lane = tid & 63, w = tid >> 6, wr = w >> 1, wc = w & 1;
    const int cl = lane & 15, kl8 = (lane >> 4) * 8;
    const int row0 = blockIdx.x * 32;
    const int myrow = row0 + wr * 16 + cl;
    const u16* hp = h + (size_t)myrow * HD + kl8;
    const float* ap = agg + (size_t)myrow * HD + kl8;

    f32x4 acc[4];
    zero_acc(acc);
    const int KC1 = 8;
    const u16* b1p = W1f + (size_t)(wc * 4 * KC1) * 512 + lane * 8;
    #pragma unroll
    for (int k0 = 0; k0 < 4; k0++) {
        bf16x8 a = *(const bf16x8*)(hp + k0 * 32);
        mfma4(a, b1p + k0 * 512, KC1 * 512, acc);
    }
    #pragma unroll
    for (int k0 = 0; k0 < 4; k0++) {
        float4 f0 = *(const float4*)(ap + k0 * 32);
        float4 f1 = *(const float4*)(ap + k0 * 32 + 4);
        bf16x8 a;
        a[0] = (short)f2b(f0.x); a[1] = (short)f2b(f0.y);
        a[2] = (short)f2b(f0.z); a[3] = (short)f2b(f0.w);
        a[4] = (short)f2b(f1.x); a[5] = (short)f2b(f1.y);
        a[6] = (short)f2b(f1.z); a[7] = (short)f2b(f1.w);
        mfma4(a, b1p + (4 + k0) * 512, KC1 * 512, acc);
    }
    store_tile<true>(tb, wr, wc, lane, acc, b1);
    __syncthreads();
    zero_acc(acc);
    gemm_tb(tb, W2f, wr, wc, lane, acc);
    __syncthreads();
    store_tile<true>(tb, wr, wc, lane, acc, b2);
    __syncthreads();
    zero_acc(acc);
    gemm_tb(tb, W3f, wr, wc, lane, acc);
    __syncthreads();
    {   // residual with old h
        const int r0 = (lane >> 4) * 4;
        #pragma unroll
        for (int ct = 0; ct < 4; ct++) {
            int col = wc * 64 + ct * 16 + cl;
            float bv = b3[col];
            #pragma unroll
            for (int i = 0; i < 4; i++) {
                float old = b2f(h[(size_t)(row0 + wr * 16 + r0 + i) * HD + col]);
                tb[(wr * 16 + r0 + i) * 136 + col] = f2b(old + acc[ct][i] + bv);
            }
        }
    }
    __syncthreads();
    {
        const int r = tid >> 3, sgi = tid & 7;
        const int grow = row0 + r;
        float4* ho = (float4*)(h + (size_t)grow * HD);
        ho[sgi]     = *(const float4*)(tb + r * 136 + sgi * 8);
        ho[8 + sgi] = *(const float4*)(tb + r * 136 + 64 + sgi * 8);
    }
}

// ---------------- decoder: h -> MLP(H,H,OUT=2) fp32 out ----------------
__global__ __launch_bounds__(256, 4) void dec_mfma(
    const u16* __restrict__ h,
    const u16* __restrict__ W1f, const float* __restrict__ b1,
    const u16* __restrict__ W2f, const float* __restrict__ b2,
    const float* __restrict__ W3, const float* __restrict__ b3,
    float* __restrict__ out) {
    __shared__ u16 tb[32 * 136];
    const int tid = threadIdx.x;
    const int lane = tid & 63, w = tid >> 6, wr = w >> 1, wc = w & 1;
    const int cl = lane & 15, kl8 = (lane >> 4) * 8;
    const int row0 = blockIdx.x * 32;
    const int myrow = row0 + wr * 16 + cl;
    const u16* hp = h + (size_t)myrow * HD + kl8;

    f32x4 acc[4];
    zero_acc(acc);
    const u16* b1p = W1f + (size_t)(wc * 4 * 4) * 512 + lane * 8;
    #pragma unroll
    for (int k0 = 0; k0 < 4; k0++) {
        bf16x8 a = *(const bf16x8*)(hp + k0 * 32);
        mfma4(a, b1p + k0 * 512, 4 * 512, acc);
    }
    store_tile<true>(tb, wr, wc, lane, acc, b1);
    __syncthreads();
    zero_acc(acc);
    gemm_tb(tb, W2f, wr, wc, lane, acc);
    __syncthreads();
    store_tile<true>(tb, wr, wc, lane, acc, b2);
    __syncthreads();
    if (tid < 64) {
        const int rr = tid >> 1, o = tid & 1;
        const int grow = row0 + rr;
        if (grow < NND) {
            float a = b3[o];
            for (int k = 0; k < HD; k++) a += b2f(tb[rr * 136 + k]) * W3[k * 2 + o];
            out[(size_t)grow * 2 + o] = a;
        }
    }
}

extern "C" void kernel_launch(void* const* d_in, const int* in_sizes, int n_in,
                              void* d_out, int out_size, void* d_ws, size_t ws_size,
                              hipStream_t stream) {
    (void)in_sizes; (void)n_in; (void)out_size; (void)ws_size;
    const float* x    = (const float*)d_in[0];
    const float* eatt = (const float*)d_in[1];
    const int*   eidx = (const int*)d_in[2];
    const float *neW1 = (const float*)d_in[3],  *neb1 = (const float*)d_in[4];
    const float *neW2 = (const float*)d_in[5],  *neb2 = (const float*)d_in[6];
    const float *neW3 = (const float*)d_in[7],  *neb3 = (const float*)d_in[8];
    const float *eeW1 = (const float*)d_in[9],  *eeb1 = (const float*)d_in[10];
    const float *eeW2 = (const float*)d_in[11], *eeb2 = (const float*)d_in[12];
    const float *eeW3 = (const float*)d_in[13], *eeb3 = (const float*)d_in[14];
    const float *peW1 = (const float*)d_in[15], *peb1 = (const float*)d_in[16];
    const float *peW2 = (const float*)d_in[17], *peb2 = (const float*)d_in[18];
    const float *peW3 = (const float*)d_in[19], *peb3 = (const float*)d_in[20];
    const float *pnW1 = (const float*)d_in[21], *pnb1 = (const float*)d_in[22];
    const float *pnW2 = (const float*)d_in[23], *pnb2 = (const float*)d_in[24];
    const float *pnW3 = (const float*)d_in[25], *pnb3 = (const float*)d_in[26];
    const float *ndW1 = (const float*)d_in[27], *ndb1 = (const float*)d_in[28];
    const float *ndW2 = (const float*)d_in[29], *ndb2 = (const float*)d_in[30];
    const float *ndW3 = (const float*)d_in[31], *ndb3 = (const float*)d_in[32];

    char* ws = (char*)d_ws;
    u16*   h   = (u16*)ws;                                   // [NNDP][HD] bf16
    u16*   e   = (u16*)(ws + 12804096);                      // [NED][HD] bf16
    float* agg = (float*)(ws + 12804096 + 102400000);        // [NNDP][HD] f32
    u16*   wts = (u16*)(ws + 12804096 + 102400000 + 25608192);

    u16* p = wts;
    u16 *neW1t = p; p += 128 * 32;
    u16 *neW2t = p; p += 128 * 128;
    u16 *neW3t = p; p += 128 * 128;
    u16 *eeW1t = p; p += 128 * 32;
    u16 *eeW2t = p; p += 128 * 128;
    u16 *eeW3t = p; p += 128 * 128;
    u16 *peW1t[NSTEP], *peW2t[NSTEP], *peW3t[NSTEP];
    u16 *pnW1t[NSTEP], *pnW2t[NSTEP], *pnW3t[NSTEP];
    for (int t = 0; t < NSTEP; t++) {
        peW1t[t] = p; p += 128 * 384;
        peW2t[t] = p; p += 128 * 128;
        peW3t[t] = p; p += 128 * 128;
    }
    for (int t = 0; t < NSTEP; t++) {
        pnW1t[t] = p; p += 128 * 256;
        pnW2t[t] = p; p += 128 * 128;
        pnW3t[t] = p; p += 128 * 128;
    }
    u16 *ndW1t = p; p += 128 * 128;
    u16 *ndW2t = p; p += 128 * 128;

    auto WP = [&](const float* s, u16* d, int K, int Kp) {
        int tot = 128 * Kp;
        wprep_frag<<<(tot + 255) / 256, 256, 0, stream>>>(s, d, K, Kp);
    };
    WP(neW1, neW1t, 4, 32);
    WP(neW2, neW2t, 128, 128);
    WP(neW3, neW3t, 128, 128);
    WP(eeW1, eeW1t, 3, 32);
    WP(eeW2, eeW2t, 128, 128);
    WP(eeW3, eeW3t, 128, 128);
    for (int t = 0; t < NSTEP; t++) {
        WP(peW1 + (size_t)t * 384 * 128, peW1t[t], 384, 384);
        WP(peW2 + (size_t)t * 128 * 128, peW2t[t], 128, 128);
        WP(peW3 + (size_t)t * 128 * 128, peW3t[t], 128, 128);
        WP(pnW1 + (size_t)t * 256 * 128, pnW1t[t], 256, 256);
        WP(pnW2 + (size_t)t * 128 * 128, pnW2t[t], 128, 128);
        WP(pnW3 + (size_t)t * 128 * 128, pnW3t[t], 128, 128);
    }
    WP(ndW1, ndW1t, 128, 128);
    WP(ndW2, ndW2t, 128, 128);

    enc_mfma<<<NNDP / 32, 256, 0, stream>>>(x, 4, NND, neW1t, neb1, neW2t, neb2, neW3t, neb3, h);
    enc_mfma<<<NED / 32, 256, 0, stream>>>(eatt, 3, NED, eeW1t, eeb1, eeW2t, eeb2, eeW3t, eeb3, e);

    for (int t = 0; t < NSTEP; t++) {
        hipMemsetAsync(agg, 0, (size_t)NNDP * HD * sizeof(float), stream);
        edge_mfma<<<NED / 32, 256, 0, stream>>>(
            h, e, eidx,
            peW1t[t], peb1 + (size_t)t * HD,
            peW2t[t], peb2 + (size_t)t * HD,
            peW3t[t], peb3 + (size_t)t * HD,
            agg);
        node_mfma<<<NNDP / 32, 256, 0, stream>>>(
            h, agg,
            pnW1t[t], pnb1 + (size_t)t * HD,
            pnW2t[t], pnb2 + (size_t)t * HD,
            pnW3t[t], pnb3 + (size_t)t * HD);
    }
    dec_mfma<<<NNDP / 32, 256, 0, stream>>>(h, ndW1t, ndb1, ndW2t, ndb2, ndW3, ndb3, (float*)d_out);
}

// Round 4
// 969.775 us; speedup vs baseline: 14.1392x; 8.9225x over previous
//
#include <hip/hip_runtime.h>
#include <cstddef>

#define NND 50000
#define NNDP 50016   // padded to multiple of 32
#define NED 400000
#define HD 128
#define NSTEP 3
#define SCAN_CHUNK 49  // 1024*49 >= NNDP

using u16 = unsigned short;
typedef __attribute__((ext_vector_type(8))) short bf16x8;
typedef __attribute__((ext_vector_type(4))) float f32x4;

__device__ __forceinline__ u16 f2b(float f) {
    union { float f; unsigned u; } v; v.f = f;
    unsigned r = v.u + 0x7FFFu + ((v.u >> 16) & 1u);
    return (u16)(r >> 16);
}
__device__ __forceinline__ float b2f(u16 u) {
    union { unsigned u; float f; } v; v.u = ((unsigned)u) << 16;
    return v.f;
}

// 4 MFMAs covering 16 rows x 64 cols for one k0-chunk of 32.
// bp points at fragment-major weights: element ((n0*KC + k0)*64 + lane)*8.
__device__ __forceinline__ void mfma4(bf16x8 a, const u16* bp, int ctStride, f32x4 (&acc)[4]) {
    bf16x8 b0 = *(const bf16x8*)(bp);
    bf16x8 b1 = *(const bf16x8*)(bp + ctStride);
    bf16x8 b2 = *(const bf16x8*)(bp + 2 * ctStride);
    bf16x8 b3 = *(const bf16x8*)(bp + 3 * ctStride);
    acc[0] = __builtin_amdgcn_mfma_f32_16x16x32_bf16(a, b0, acc[0], 0, 0, 0);
    acc[1] = __builtin_amdgcn_mfma_f32_16x16x32_bf16(a, b1, acc[1], 0, 0, 0);
    acc[2] = __builtin_amdgcn_mfma_f32_16x16x32_bf16(a, b2, acc[2], 0, 0, 0);
    acc[3] = __builtin_amdgcn_mfma_f32_16x16x32_bf16(a, b3, acc[3], 0, 0, 0);
}

__device__ __forceinline__ void zero_acc(f32x4 (&acc)[4]) {
    #pragma unroll
    for (int i = 0; i < 4; i++) acc[i] = (f32x4)(0.0f);
}

// K=128 layer with A in LDS t-buffer (stride 136 u16), weights fragment-major (KC=4).
__device__ __forceinline__ void gemm_tb(const u16* tb, const u16* __restrict__ Wf,
                                        int wr, int wc, int lane, f32x4 (&acc)[4]) {
    const int cl = lane & 15, kl8 = (lane >> 4) * 8;
    const u16* ar = tb + (wr * 16 + cl) * 136 + kl8;
    const u16* bp = Wf + (size_t)(wc * 4 * 4) * 512 + lane * 8;
    #pragma unroll
    for (int k0 = 0; k0 < 4; k0++) {
        bf16x8 a = *(const bf16x8*)(ar + k0 * 32);
        mfma4(a, bp + k0 * 512, 4 * 512, acc);
    }
}

// C/D layout (m89-verified): col = lane&15, row = (lane>>4)*4 + reg.
template <bool RELU>
__device__ __forceinline__ void store_tile(u16* T, int wr, int wc, int lane,
                                           const f32x4 (&acc)[4], const float* __restrict__ bias) {
    const int cl = lane & 15;
    const int r0 = wr * 16 + (lane >> 4) * 4;
    #pragma unroll
    for (int ct = 0; ct < 4; ct++) {
        int col = wc * 64 + ct * 16 + cl;
        float bv = bias[col];
        #pragma unroll
        for (int i = 0; i < 4; i++) {
            float v = acc[ct][i] + bv;
            if (RELU) v = fmaxf(v, 0.0f);
            T[(r0 + i) * 136 + col] = f2b(v);
        }
    }
}

// ---------------- CSR build ----------------
__global__ void count_kernel(const int* __restrict__ eidx, int* __restrict__ counts) {
    int i = blockIdx.x * 256 + threadIdx.x;
    if (i < NED) atomicAdd(&counts[eidx[NED + i]], 1);
}

__global__ __launch_bounds__(1024) void scan_kernel(const int* __restrict__ counts,
                                                    int* __restrict__ offsets,
                                                    int* __restrict__ cursors) {
    __shared__ int part[1024];
    const int t = threadIdx.x;
    const int base = t * SCAN_CHUNK;
    int s = 0;
    for (int j = 0; j < SCAN_CHUNK; j++) {
        int idx = base + j;
        if (idx < NNDP) s += counts[idx];
    }
    part[t] = s;
    __syncthreads();
    for (int ofs = 1; ofs < 1024; ofs <<= 1) {
        int v = (t >= ofs) ? part[t - ofs] : 0;
        __syncthreads();
        part[t] += v;
        __syncthreads();
    }
    int run = (t > 0) ? part[t - 1] : 0;  // exclusive prefix at chunk start
    for (int j = 0; j < SCAN_CHUNK; j++) {
        int idx = base + j;
        if (idx < NNDP) {
            offsets[idx] = run;
            cursors[idx] = run;
            run += counts[idx];
        }
    }
    if (t == 1023) offsets[NNDP] = part[1023];
}

__global__ void fill_kernel(const int* __restrict__ eidx, int* __restrict__ cursors,
                            int* __restrict__ perm, int* __restrict__ srcp,
                            int* __restrict__ dstp) {
    int i = blockIdx.x * 256 + threadIdx.x;
    if (i >= NED) return;
    int d = eidx[NED + i];
    int pos = atomicAdd(&cursors[d], 1);
    perm[pos] = i;
    srcp[pos] = eidx[i];
    dstp[pos] = d;
}

// ---------------- weight prep: fp32 [K][128] -> bf16 fragment-major ----------------
__global__ void wprep_frag(const float* __restrict__ src, u16* __restrict__ dst, int K, int Kp) {
    int idx = blockIdx.x * 256 + threadIdx.x;
    if (idx >= 128 * Kp) return;
    int j = idx & 7, lane = (idx >> 3) & 63, rest = idx >> 9;
    int KC = Kp >> 5;
    int k0 = rest % KC, n0 = rest / KC;
    int n = n0 * 16 + (lane & 15);
    int k = k0 * 32 + (lane >> 4) * 8 + j;
    float v = (k < K) ? src[(size_t)k * 128 + n] : 0.0f;
    dst[idx] = f2b(v);
}

// ---------------- encoder: fp32 [rows][Kin] -> MLP(Kin,H,H,H) -> bf16 out ----------------
// If perm != nullptr, row i reads input row perm[i] (used to emit e in dst-sorted order).
__global__ __launch_bounds__(256, 4) void enc_mfma(
    const float* __restrict__ in, int Kin, int nrows, const int* __restrict__ perm,
    const u16* __restrict__ W1f, const float* __restrict__ b1,
    const u16* __restrict__ W2f, const float* __restrict__ b2,
    const u16* __restrict__ W3f, const float* __restrict__ b3,
    u16* __restrict__ out) {
    __shared__ u16 tb[32 * 136];
    const int tid = threadIdx.x;
    const int lane = tid & 63, w = tid >> 6, wr = w >> 1, wc = w & 1;
    const int cl = lane & 15, kl8 = (lane >> 4) * 8;
    const int row0 = blockIdx.x * 32;
    const int grow = row0 + wr * 16 + cl;

    f32x4 acc[4];
    zero_acc(acc);
    bf16x8 a = {0, 0, 0, 0, 0, 0, 0, 0};
    if (kl8 == 0 && grow < nrows) {
        int irow = perm ? perm[grow] : grow;
        const float* xr = in + (size_t)irow * Kin;
        if (Kin == 4) {
            float4 v = *(const float4*)xr;
            a[0] = (short)f2b(v.x); a[1] = (short)f2b(v.y);
            a[2] = (short)f2b(v.z); a[3] = (short)f2b(v.w);
        } else {
            a[0] = (short)f2b(xr[0]); a[1] = (short)f2b(xr[1]); a[2] = (short)f2b(xr[2]);
        }
    }
    mfma4(a, W1f + (size_t)(wc * 4) * 512 + lane * 8, 512, acc);
    store_tile<true>(tb, wr, wc, lane, acc, b1);
    __syncthreads();
    zero_acc(acc);
    gemm_tb(tb, W2f, wr, wc, lane, acc);
    __syncthreads();
    store_tile<true>(tb, wr, wc, lane, acc, b2);
    __syncthreads();
    zero_acc(acc);
    gemm_tb(tb, W3f, wr, wc, lane, acc);
    __syncthreads();
    store_tile<false>(tb, wr, wc, lane, acc, b3);
    __syncthreads();
    const int r = tid >> 3, sgi = tid & 7;
    const int orow = row0 + r;
    if (orow < nrows) {
        float4* dst = (float4*)(out + (size_t)orow * HD);
        dst[sgi]     = *(const float4*)(tb + r * 136 + sgi * 8);
        dst[8 + sgi] = *(const float4*)(tb + r * 136 + 64 + sgi * 8);
    }
}

// ---------------- edge step (dst-sorted storage): gather-frag -> MLP(3H,H,H) -> +e -> store e ----------------
__global__ __launch_bounds__(256, 4) void edge_mfma(
    const u16* __restrict__ h, u16* __restrict__ e,
    const int* __restrict__ srcp, const int* __restrict__ dstp,
    const u16* __restrict__ W1f, const float* __restrict__ b1,
    const u16* __restrict__ W2f, const float* __restrict__ b2,
    const u16* __restrict__ W3f, const float* __restrict__ b3) {
    __shared__ u16 tb[32 * 136];
    const int tid = threadIdx.x;
    const int lane = tid & 63, w = tid >> 6, wr = w >> 1, wc = w & 1;
    const int cl = lane & 15, kl8 = (lane >> 4) * 8;
    const int row0 = blockIdx.x * 32;
    const int myrow = row0 + wr * 16 + cl;
    const int s = srcp[myrow];
    const int d = dstp[myrow];
    const u16* hs = h + (size_t)s * HD + kl8;
    const u16* hd = h + (size_t)d * HD + kl8;
    const u16* ep = e + (size_t)myrow * HD + kl8;

    f32x4 acc[4];
    zero_acc(acc);
    const int KC1 = 12;
    const u16* b1p = W1f + (size_t)(wc * 4 * KC1) * 512 + lane * 8;
    #pragma unroll
    for (int k0 = 0; k0 < 4; k0++) {
        bf16x8 a = *(const bf16x8*)(hs + k0 * 32);
        mfma4(a, b1p + k0 * 512, KC1 * 512, acc);
    }
    #pragma unroll
    for (int k0 = 0; k0 < 4; k0++) {
        bf16x8 a = *(const bf16x8*)(hd + k0 * 32);
        mfma4(a, b1p + (4 + k0) * 512, KC1 * 512, acc);
    }
    #pragma unroll
    for (int k0 = 0; k0 < 4; k0++) {
        bf16x8 a = *(const bf16x8*)(ep + k0 * 32);
        mfma4(a, b1p + (8 + k0) * 512, KC1 * 512, acc);
    }
    store_tile<true>(tb, wr, wc, lane, acc, b1);
    __syncthreads();
    zero_acc(acc);
    gemm_tb(tb, W2f, wr, wc, lane, acc);
    __syncthreads();
    store_tile<true>(tb, wr, wc, lane, acc, b2);
    __syncthreads();
    zero_acc(acc);
    gemm_tb(tb, W3f, wr, wc, lane, acc);
    __syncthreads();
    {   // residual with old e (sequential re-read, L2-hot) + bias, write to tb
        const int r0 = (lane >> 4) * 4;
        #pragma unroll
        for (int ct = 0; ct < 4; ct++) {
            int col = wc * 64 + ct * 16 + cl;
            float bv = b3[col];
            #pragma unroll
            for (int i = 0; i < 4; i++) {
                float old = b2f(e[(size_t)(row0 + wr * 16 + r0 + i) * HD + col]);
                tb[(wr * 16 + r0 + i) * 136 + col] = f2b(old + acc[ct][i] + bv);
            }
        }
    }
    __syncthreads();
    {
        const int r = tid >> 3, sgi = tid & 7;
        const int grow = row0 + r;
        float4* eo = (float4*)(e + (size_t)grow * HD);
        eo[sgi]     = *(const float4*)(tb + r * 136 + sgi * 8);
        eo[8 + sgi] = *(const float4*)(tb + r * 136 + 64 + sgi * 8);
    }
}

// ---------------- node step: CSR agg (sequential e-stream) + [h|agg] -> MLP(2H,H,H) -> +h ----------------
__global__ __launch_bounds__(256, 4) void node_mfma(
    u16* __restrict__ h, const u16* __restrict__ e, const int* __restrict__ offsets,
    const u16* __restrict__ W1f, const float* __restrict__ b1,
    const u16* __restrict__ W2f, const float* __restrict__ b2,
    const u16* __restrict__ W3f, const float* __restrict__ b3) {
    __shared__ u16 tb[32 * 136];
    __shared__ u16 aggT[32 * 136];
    const int tid = threadIdx.x;
    const int lane = tid & 63, w = tid >> 6, wr = w >> 1, wc = w & 1;
    const int cl = lane & 15, kl8 = (lane >> 4) * 8;
    const int row0 = blockIdx.x * 32;

    {   // aggregation: 8 threads per node row, each 16 cols; e rows are contiguous per node
        const int r = tid >> 3, sgi = tid & 7;
        const int node = row0 + r;
        const int beg = offsets[node], end = offsets[node + 1];
        float s[16];
        #pragma unroll
        for (int k = 0; k < 16; k++) s[k] = 0.0f;
        for (int j = beg; j < end; j++) {
            const bf16x8* ev = (const bf16x8*)(e + (size_t)j * HD + sgi * 16);
            bf16x8 v0 = ev[0], v1 = ev[1];
            #pragma unroll
            for (int k = 0; k < 8; k++) {
                s[k]     += b2f((u16)v0[k]);
                s[8 + k] += b2f((u16)v1[k]);
            }
        }
        bf16x8 o0, o1;
        #pragma unroll
        for (int k = 0; k < 8; k++) {
            o0[k] = (short)f2b(s[k]);
            o1[k] = (short)f2b(s[8 + k]);
        }
        *(bf16x8*)(aggT + r * 136 + sgi * 16) = o0;
        *(bf16x8*)(aggT + r * 136 + sgi * 16 + 8) = o1;
    }
    __syncthreads();

    const int myrow = row0 + wr * 16 + cl;
    const u16* hp = h + (size_t)myrow * HD + kl8;
    const u16* ar = aggT + (wr * 16 + cl) * 136 + kl8;

    f32x4 acc[4];
    zero_acc(acc);
    const int KC1 = 8;
    const u16* b1p = W1f + (size_t)(wc * 4 * KC1) * 512 + lane * 8;
    #pragma unroll
    for (int k0 = 0; k0 < 4; k0++) {
        bf16x8 a = *(const bf16x8*)(hp + k0 * 32);
        mfma4(a, b1p + k0 * 512, KC1 * 512, acc);
    }
    #pragma unroll
    for (int k0 = 0; k0 < 4; k0++) {
        bf16x8 a = *(const bf16x8*)(ar + k0 * 32);
        mfma4(a, b1p + (4 + k0) * 512, KC1 * 512, acc);
    }
    store_tile<true>(tb, wr, wc, lane, acc, b1);
    __syncthreads();
    zero_acc(acc);
    gemm_tb(tb, W2f, wr, wc, lane, acc);
    __syncthreads();
    store_tile<true>(tb, wr, wc, lane, acc, b2);
    __syncthreads();
    zero_acc(acc);
    gemm_tb(tb, W3f, wr, wc, lane, acc);
    __syncthreads();
    {   // residual with old h
        const int r0 = (lane >> 4) * 4;
        #pragma unroll
        for (int ct = 0; ct < 4; ct++) {
            int col = wc * 64 + ct * 16 + cl;
            float bv = b3[col];
            #pragma unroll
            for (int i = 0; i < 4; i++) {
                float old = b2f(h[(size_t)(row0 + wr * 16 + r0 + i) * HD + col]);
                tb[(wr * 16 + r0 + i) * 136 + col] = f2b(old + acc[ct][i] + bv);
            }
        }
    }
    __syncthreads();
    {
        const int r = tid >> 3, sgi = tid & 7;
        const int grow = row0 + r;
        float4* ho = (float4*)(h + (size_t)grow * HD);
        ho[sgi]     = *(const float4*)(tb + r * 136 + sgi * 8);
        ho[8 + sgi] = *(const float4*)(tb + r * 136 + 64 + sgi * 8);
    }
}

// ---------------- decoder: h -> MLP(H,H,OUT=2) fp32 out ----------------
__global__ __launch_bounds__(256, 4) void dec_mfma(
    const u16* __restrict__ h,
    const u16* __restrict__ W1f, const float* __restrict__ b1,
    const u16* __restrict__ W2f, const float* __restrict__ b2,
    const float* __restrict__ W3, const float* __restrict__ b3,
    float* __restrict__ out) {
    __shared__ u16 tb[32 * 136];
    const int tid = threadIdx.x;
    const int lane = tid & 63, w = tid >> 6, wr = w >> 1, wc = w & 1;
    const int cl = lane & 15, kl8 = (lane >> 4) * 8;
    const int row0 = blockIdx.x * 32;
    const int myrow = row0 + wr * 16 + cl;
    const u16* hp = h + (size_t)myrow * HD + kl8;

    f32x4 acc[4];
    zero_acc(acc);
    const u16* b1p = W1f + (size_t)(wc * 4 * 4) * 512 + lane * 8;
    #pragma unroll
    for (int k0 = 0; k0 < 4; k0++) {
        bf16x8 a = *(const bf16x8*)(hp + k0 * 32);
        mfma4(a, b1p + k0 * 512, 4 * 512, acc);
    }
    store_tile<true>(tb, wr, wc, lane, acc, b1);
    __syncthreads();
    zero_acc(acc);
    gemm_tb(tb, W2f, wr, wc, lane, acc);
    __syncthreads();
    store_tile<true>(tb, wr, wc, lane, acc, b2);
    __syncthreads();
    if (tid < 64) {
        const int rr = tid >> 1, o = tid & 1;
        const int grow = row0 + rr;
        if (grow < NND) {
            float a = b3[o];
            for (int k = 0; k < HD; k++) a += b2f(tb[rr * 136 + k]) * W3[k * 2 + o];
            out[(size_t)grow * 2 + o] = a;
        }
    }
}

extern "C" void kernel_launch(void* const* d_in, const int* in_sizes, int n_in,
                              void* d_out, int out_size, void* d_ws, size_t ws_size,
                              hipStream_t stream) {
    (void)in_sizes; (void)n_in; (void)out_size; (void)ws_size;
    const float* x    = (const float*)d_in[0];
    const float* eatt = (const float*)d_in[1];
    const int*   eidx = (const int*)d_in[2];
    const float *neW1 = (const float*)d_in[3],  *neb1 = (const float*)d_in[4];
    const float *neW2 = (const float*)d_in[5],  *neb2 = (const float*)d_in[6];
    const float *neW3 = (const float*)d_in[7],  *neb3 = (const float*)d_in[8];
    const float *eeW1 = (const float*)d_in[9],  *eeb1 = (const float*)d_in[10];
    const float *eeW2 = (const float*)d_in[11], *eeb2 = (const float*)d_in[12];
    const float *eeW3 = (const float*)d_in[13], *eeb3 = (const float*)d_in[14];
    const float *peW1 = (const float*)d_in[15], *peb1 = (const float*)d_in[16];
    const float *peW2 = (const float*)d_in[17], *peb2 = (const float*)d_in[18];
    const float *peW3 = (const float*)d_in[19], *peb3 = (const float*)d_in[20];
    const float *pnW1 = (const float*)d_in[21], *pnb1 = (const float*)d_in[22];
    const float *pnW2 = (const float*)d_in[23], *pnb2 = (const float*)d_in[24];
    const float *pnW3 = (const float*)d_in[25], *pnb3 = (const float*)d_in[26];
    const float *ndW1 = (const float*)d_in[27], *ndb1 = (const float*)d_in[28];
    const float *ndW2 = (const float*)d_in[29], *ndb2 = (const float*)d_in[30];
    const float *ndW3 = (const float*)d_in[31], *ndb3 = (const float*)d_in[32];

    char* ws = (char*)d_ws;
    u16*   h       = (u16*)ws;                          // [NNDP][HD] bf16
    u16*   e       = (u16*)(ws + 12804096);             // [NED][HD] bf16 (dst-sorted order)
    int*   counts  = (int*)(ws + 115204096);            // [NNDP]
    int*   cursors = (int*)(ws + 115404160);            // [NNDP]
    int*   offsets = (int*)(ws + 115604224);            // [NNDP+1]
    int*   perm    = (int*)(ws + 115804416);            // [NED]
    int*   srcp    = (int*)(ws + 117404416);            // [NED]
    int*   dstp    = (int*)(ws + 119004416);            // [NED]
    u16*   wts     = (u16*)(ws + 120604416);

    u16* p = wts;
    u16 *neW1t = p; p += 128 * 32;
    u16 *neW2t = p; p += 128 * 128;
    u16 *neW3t = p; p += 128 * 128;
    u16 *eeW1t = p; p += 128 * 32;
    u16 *eeW2t = p; p += 128 * 128;
    u16 *eeW3t = p; p += 128 * 128;
    u16 *peW1t[NSTEP], *peW2t[NSTEP], *peW3t[NSTEP];
    u16 *pnW1t[NSTEP], *pnW2t[NSTEP], *pnW3t[NSTEP];
    for (int t = 0; t < NSTEP; t++) {
        peW1t[t] = p; p += 128 * 384;
        peW2t[t] = p; p += 128 * 128;
        peW3t[t] = p; p += 128 * 128;
    }
    for (int t = 0; t < NSTEP; t++) {
        pnW1t[t] = p; p += 128 * 256;
        pnW2t[t] = p; p += 128 * 128;
        pnW3t[t] = p; p += 128 * 128;
    }
    u16 *ndW1t = p; p += 128 * 128;
    u16 *ndW2t = p; p += 128 * 128;

    // --- CSR build (all int ops; rebuilt every replay, deterministic modulo within-dst order) ---
    hipMemsetAsync(counts, 0, NNDP * sizeof(int), stream);
    count_kernel<<<(NED + 255) / 256, 256, 0, stream>>>(eidx, counts);
    scan_kernel<<<1, 1024, 0, stream>>>(counts, offsets, cursors);
    fill_kernel<<<(NED + 255) / 256, 256, 0, stream>>>(eidx, cursors, perm, srcp, dstp);

    // --- weight prep ---
    auto WP = [&](const float* s, u16* d, int K, int Kp) {
        int tot = 128 * Kp;
        wprep_frag<<<(tot + 255) / 256, 256, 0, stream>>>(s, d, K, Kp);
    };
    WP(neW1, neW1t, 4, 32);
    WP(neW2, neW2t, 128, 128);
    WP(neW3, neW3t, 128, 128);
    WP(eeW1, eeW1t, 3, 32);
    WP(eeW2, eeW2t, 128, 128);
    WP(eeW3, eeW3t, 128, 128);
    for (int t = 0; t < NSTEP; t++) {
        WP(peW1 + (size_t)t * 384 * 128, peW1t[t], 384, 384);
        WP(peW2 + (size_t)t * 128 * 128, peW2t[t], 128, 128);
        WP(peW3 + (size_t)t * 128 * 128, peW3t[t], 128, 128);
        WP(pnW1 + (size_t)t * 256 * 128, pnW1t[t], 256, 256);
        WP(pnW2 + (size_t)t * 128 * 128, pnW2t[t], 128, 128);
        WP(pnW3 + (size_t)t * 128 * 128, pnW3t[t], 128, 128);
    }
    WP(ndW1, ndW1t, 128, 128);
    WP(ndW2, ndW2t, 128, 128);

    enc_mfma<<<NNDP / 32, 256, 0, stream>>>(x, 4, NND, nullptr,
                                            neW1t, neb1, neW2t, neb2, neW3t, neb3, h);
    enc_mfma<<<NED / 32, 256, 0, stream>>>(eatt, 3, NED, perm,
                                           eeW1t, eeb1, eeW2t, eeb2, eeW3t, eeb3, e);

    for (int t = 0; t < NSTEP; t++) {
        edge_mfma<<<NED / 32, 256, 0, stream>>>(
            h, e, srcp, dstp,
            peW1t[t], peb1 + (size_t)t * HD,
            peW2t[t], peb2 + (size_t)t * HD,
            peW3t[t], peb3 + (size_t)t * HD);
        node_mfma<<<NNDP / 32, 256, 0, stream>>>(
            h, e, offsets,
            pnW1t[t], pnb1 + (size_t)t * HD,
            pnW2t[t], pnb2 + (size_t)t * HD,
            pnW3t[t], pnb3 + (size_t)t * HD);
    }
    dec_mfma<<<NNDP / 32, 256, 0, stream>>>(h, ndW1t, ndb1, ndW2t, ndb2, ndW3, ndb3, (float*)d_out);
}

// Round 5
// 870.801 us; speedup vs baseline: 15.7462x; 1.1137x over previous
//
#include <hip/hip_runtime.h>
#include <cstddef>

#define NND 50000
#define NNDP 50048   // padded: multiple of 128
#define NED 400000
#define HD 128
#define NSTEP 3
#define SCAN_CHUNK 49  // 1024*49 >= NNDP+1

using u16 = unsigned short;
typedef __attribute__((ext_vector_type(8))) short bf16x8;
typedef __attribute__((ext_vector_type(4))) float f32x4;

__device__ __forceinline__ u16 f2b(float f) {
    union { float f; unsigned u; } v; v.f = f;
    unsigned r = v.u + 0x7FFFu + ((v.u >> 16) & 1u);
    return (u16)(r >> 16);
}
__device__ __forceinline__ float b2f(u16 u) {
    union { unsigned u; float f; } v; v.u = ((unsigned)u) << 16;
    return v.f;
}

template <int RG>
__device__ __forceinline__ void zero_accs(f32x4 (&acc)[RG][4]) {
    #pragma unroll
    for (int g = 0; g < RG; g++)
        #pragma unroll
        for (int i = 0; i < 4; i++) acc[g][i] = (f32x4)(0.0f);
}

__device__ __forceinline__ void mfma4g(bf16x8 a, const bf16x8 (&b)[4], f32x4 (&accg)[4]) {
    accg[0] = __builtin_amdgcn_mfma_f32_16x16x32_bf16(a, b[0], accg[0], 0, 0, 0);
    accg[1] = __builtin_amdgcn_mfma_f32_16x16x32_bf16(a, b[1], accg[1], 0, 0, 0);
    accg[2] = __builtin_amdgcn_mfma_f32_16x16x32_bf16(a, b[2], accg[2], 0, 0, 0);
    accg[3] = __builtin_amdgcn_mfma_f32_16x16x32_bf16(a, b[3], accg[3], 0, 0, 0);
}

// K=128 layer, A from LDS tb (stride 136), weights fragment-major KC=4.
// Each B-fragment set is reused for RG row-groups.
template <int RG>
__device__ __forceinline__ void gemm_tb_rg(const u16* tb, int rbase,
                                           const u16* __restrict__ Wf,
                                           int wc, int lane, f32x4 (&acc)[RG][4]) {
    const int cl = lane & 15, kl8 = (lane >> 4) * 8;
    const u16* bp = Wf + (size_t)(wc * 16) * 512 + lane * 8;
    #pragma unroll
    for (int k0 = 0; k0 < 4; k0++) {
        bf16x8 b[4];
        #pragma unroll
        for (int ct = 0; ct < 4; ct++) b[ct] = *(const bf16x8*)(bp + (ct * 4 + k0) * 512);
        #pragma unroll
        for (int g = 0; g < RG; g++) {
            bf16x8 a = *(const bf16x8*)(tb + (rbase + g * 16 + cl) * 136 + k0 * 32 + kl8);
            mfma4g(a, b, acc[g]);
        }
    }
}

// C/D layout (m89-verified): col = lane&15, row = (lane>>4)*4 + reg.
template <int RG, bool RELU>
__device__ __forceinline__ void store_tile_rg(u16* T, int rbase, int wc, int lane,
        const f32x4 (&acc)[RG][4], const float* __restrict__ bias) {
    const int cl = lane & 15;
    #pragma unroll
    for (int g = 0; g < RG; g++) {
        const int r0 = rbase + g * 16 + (lane >> 4) * 4;
        #pragma unroll
        for (int ct = 0; ct < 4; ct++) {
            int col = wc * 64 + ct * 16 + cl;
            float bv = bias[col];
            #pragma unroll
            for (int i = 0; i < 4; i++) {
                float v = acc[g][ct][i] + bv;
                if (RELU) v = fmaxf(v, 0.0f);
                T[(r0 + i) * 136 + col] = f2b(v);
            }
        }
    }
}

// ---------------- CSR build ----------------
__global__ void count_kernel(const int* __restrict__ eidx, int* __restrict__ counts) {
    int i = blockIdx.x * 256 + threadIdx.x;
    if (i < NED) atomicAdd(&counts[eidx[NED + i]], 1);
}

__global__ __launch_bounds__(1024) void scan_kernel(const int* __restrict__ counts,
                                                    int* __restrict__ offsets,
                                                    int* __restrict__ cursors) {
    __shared__ int part[1024];
    const int t = threadIdx.x;
    const int base = t * SCAN_CHUNK;
    int s = 0;
    for (int j = 0; j < SCAN_CHUNK; j++) {
        int idx = base + j;
        if (idx < NNDP) s += counts[idx];
    }
    part[t] = s;
    __syncthreads();
    for (int ofs = 1; ofs < 1024; ofs <<= 1) {
        int v = (t >= ofs) ? part[t - ofs] : 0;
        __syncthreads();
        part[t] += v;
        __syncthreads();
    }
    int run = (t > 0) ? part[t - 1] : 0;
    for (int j = 0; j < SCAN_CHUNK; j++) {
        int idx = base + j;
        if (idx < NNDP) {
            offsets[idx] = run;
            cursors[idx] = run;
            run += counts[idx];
        }
    }
    if (t == 1023) offsets[NNDP] = part[1023];
}

__global__ void fill_kernel(const int* __restrict__ eidx, int* __restrict__ cursors,
                            int* __restrict__ perm, int* __restrict__ srcp,
                            int* __restrict__ dstp) {
    int i = blockIdx.x * 256 + threadIdx.x;
    if (i >= NED) return;
    int d = eidx[NED + i];
    int pos = atomicAdd(&cursors[d], 1);
    perm[pos] = i;
    srcp[pos] = eidx[i];
    dstp[pos] = d;
}

// ---------------- weight prep: fp32 [K][128] -> bf16 fragment-major ----------------
__global__ void wprep_frag(const float* __restrict__ src, u16* __restrict__ dst, int K, int Kp) {
    int idx = blockIdx.x * 256 + threadIdx.x;
    if (idx >= 128 * Kp) return;
    int j = idx & 7, lane = (idx >> 3) & 63, rest = idx >> 9;
    int KC = Kp >> 5;
    int k0 = rest % KC, n0 = rest / KC;
    int n = n0 * 16 + (lane & 15);
    int k = k0 * 32 + (lane >> 4) * 8 + j;
    float v = (k < K) ? src[(size_t)k * 128 + n] : 0.0f;
    dst[idx] = f2b(v);
}

// ---------------- encoder (BM=64, RG=2) ----------------
__global__ __launch_bounds__(256, 4) void enc_mfma(
    const float* __restrict__ in, int Kin, int nrows, const int* __restrict__ perm,
    const u16* __restrict__ W1f, const float* __restrict__ b1,
    const u16* __restrict__ W2f, const float* __restrict__ b2,
    const u16* __restrict__ W3f, const float* __restrict__ b3,
    u16* __restrict__ out) {
    __shared__ u16 tb[64 * 136];
    const int tid = threadIdx.x;
    const int lane = tid & 63, w = tid >> 6, wr = w >> 1, wc = w & 1;
    const int cl = lane & 15, kl8 = (lane >> 4) * 8;
    const int row0 = blockIdx.x * 64;
    const int rbase = wr * 32;

    f32x4 acc[2][4];
    zero_accs<2>(acc);
    bf16x8 a[2];
    #pragma unroll
    for (int g = 0; g < 2; g++) {
        a[g] = (bf16x8){0, 0, 0, 0, 0, 0, 0, 0};
        int grow = row0 + rbase + g * 16 + cl;
        if (kl8 == 0 && grow < nrows) {
            int irow = perm ? perm[grow] : grow;
            const float* xr = in + (size_t)irow * Kin;
            if (Kin == 4) {
                float4 v = *(const float4*)xr;
                a[g][0] = (short)f2b(v.x); a[g][1] = (short)f2b(v.y);
                a[g][2] = (short)f2b(v.z); a[g][3] = (short)f2b(v.w);
            } else {
                a[g][0] = (short)f2b(xr[0]); a[g][1] = (short)f2b(xr[1]);
                a[g][2] = (short)f2b(xr[2]);
            }
        }
    }
    {
        const u16* b1p = W1f + (size_t)(wc * 4) * 512 + lane * 8;  // KC=1
        bf16x8 b[4];
        #pragma unroll
        for (int ct = 0; ct < 4; ct++) b[ct] = *(const bf16x8*)(b1p + ct * 512);
        #pragma unroll
        for (int g = 0; g < 2; g++) mfma4g(a[g], b, acc[g]);
    }
    store_tile_rg<2, true>(tb, rbase, wc, lane, acc, b1);
    __syncthreads();
    zero_accs<2>(acc);
    gemm_tb_rg<2>(tb, rbase, W2f, wc, lane, acc);
    __syncthreads();
    store_tile_rg<2, true>(tb, rbase, wc, lane, acc, b2);
    __syncthreads();
    zero_accs<2>(acc);
    gemm_tb_rg<2>(tb, rbase, W3f, wc, lane, acc);
    __syncthreads();
    store_tile_rg<2, false>(tb, rbase, wc, lane, acc, b3);
    __syncthreads();
    #pragma unroll
    for (int p = 0; p < 2; p++) {
        const int r = p * 32 + (tid >> 3), sgi = tid & 7;
        const int orow = row0 + r;
        if (orow < nrows) {
            float4* dst = (float4*)(out + (size_t)orow * HD);
            dst[sgi]     = *(const float4*)(tb + r * 136 + sgi * 8);
            dst[8 + sgi] = *(const float4*)(tb + r * 136 + 64 + sgi * 8);
        }
    }
}

// ---------------- edge step (BM=128, RG=4): gather -> MLP(3H,H,H) -> +e -> store e ----------------
__global__ __launch_bounds__(256, 3) void edge_mfma(
    const u16* __restrict__ h, u16* __restrict__ e,
    const int* __restrict__ srcp, const int* __restrict__ dstp,
    const u16* __restrict__ W1f, const float* __restrict__ b1,
    const u16* __restrict__ W2f, const float* __restrict__ b2,
    const u16* __restrict__ W3f, const float* __restrict__ b3) {
    __shared__ u16 tb[128 * 136];
    const int tid = threadIdx.x;
    const int lane = tid & 63, w = tid >> 6, wr = w >> 1, wc = w & 1;
    const int cl = lane & 15, kl8 = (lane >> 4) * 8;
    const int row0 = blockIdx.x * 128;
    const int rbase = wr * 64;

    const u16 *hsv[4], *hdv[4], *epv[4];
    #pragma unroll
    for (int g = 0; g < 4; g++) {
        int myrow = row0 + rbase + g * 16 + cl;
        hsv[g] = h + (size_t)srcp[myrow] * HD + kl8;
        hdv[g] = h + (size_t)dstp[myrow] * HD + kl8;
        epv[g] = e + (size_t)myrow * HD + kl8;
    }

    f32x4 acc[4][4];
    zero_accs<4>(acc);
    const u16* b1p = W1f + (size_t)(wc * 48) * 512 + lane * 8;  // KC1=12
    #pragma unroll
    for (int k0 = 0; k0 < 4; k0++) {   // h[src] section
        bf16x8 b[4];
        #pragma unroll
        for (int ct = 0; ct < 4; ct++) b[ct] = *(const bf16x8*)(b1p + (ct * 12 + k0) * 512);
        #pragma unroll
        for (int g = 0; g < 4; g++) {
            bf16x8 a = *(const bf16x8*)(hsv[g] + k0 * 32);
            mfma4g(a, b, acc[g]);
        }
    }
    #pragma unroll
    for (int k0 = 0; k0 < 4; k0++) {   // h[dst] section
        bf16x8 b[4];
        #pragma unroll
        for (int ct = 0; ct < 4; ct++) b[ct] = *(const bf16x8*)(b1p + (ct * 12 + 4 + k0) * 512);
        #pragma unroll
        for (int g = 0; g < 4; g++) {
            bf16x8 a = *(const bf16x8*)(hdv[g] + k0 * 32);
            mfma4g(a, b, acc[g]);
        }
    }
    #pragma unroll
    for (int k0 = 0; k0 < 4; k0++) {   // e section
        bf16x8 b[4];
        #pragma unroll
        for (int ct = 0; ct < 4; ct++) b[ct] = *(const bf16x8*)(b1p + (ct * 12 + 8 + k0) * 512);
        #pragma unroll
        for (int g = 0; g < 4; g++) {
            bf16x8 a = *(const bf16x8*)(epv[g] + k0 * 32);
            mfma4g(a, b, acc[g]);
        }
    }
    store_tile_rg<4, true>(tb, rbase, wc, lane, acc, b1);
    __syncthreads();
    zero_accs<4>(acc);
    gemm_tb_rg<4>(tb, rbase, W2f, wc, lane, acc);
    __syncthreads();
    store_tile_rg<4, true>(tb, rbase, wc, lane, acc, b2);
    __syncthreads();
    zero_accs<4>(acc);
    gemm_tb_rg<4>(tb, rbase, W3f, wc, lane, acc);
    __syncthreads();
    #pragma unroll
    for (int g = 0; g < 4; g++) {   // residual with old e (L1/L2-hot re-read)
        const int r0 = rbase + g * 16 + (lane >> 4) * 4;
        #pragma unroll
        for (int ct = 0; ct < 4; ct++) {
            int col = wc * 64 + ct * 16 + cl;
            float bv = b3[col];
            #pragma unroll
            for (int i = 0; i < 4; i++) {
                float old = b2f(e[(size_t)(row0 + r0 + i) * HD + col]);
                tb[(r0 + i) * 136 + col] = f2b(old + acc[g][ct][i] + bv);
            }
        }
    }
    __syncthreads();
    #pragma unroll
    for (int p = 0; p < 4; p++) {
        const int r = p * 32 + (tid >> 3), sgi = tid & 7;
        const int grow = row0 + r;
        float4* eo = (float4*)(e + (size_t)grow * HD);
        eo[sgi]     = *(const float4*)(tb + r * 136 + sgi * 8);
        eo[8 + sgi] = *(const float4*)(tb + r * 136 + 64 + sgi * 8);
    }
}

// ---------------- node step (BM=64, RG=2): CSR agg + [h|agg] MLP(2H,H,H) -> +h ----------------
__global__ __launch_bounds__(256, 3) void node_mfma(
    u16* __restrict__ h, const u16* __restrict__ e, const int* __restrict__ offsets,
    const u16* __restrict__ W1f, const float* __restrict__ b1,
    const u16* __restrict__ W2f, const float* __restrict__ b2,
    const u16* __restrict__ W3f, const float* __restrict__ b3) {
    __shared__ u16 tb[64 * 136];
    __shared__ u16 aggT[64 * 136];
    const int tid = threadIdx.x;
    const int lane = tid & 63, w = tid >> 6, wr = w >> 1, wc = w & 1;
    const int cl = lane & 15, kl8 = (lane >> 4) * 8;
    const int row0 = blockIdx.x * 64;
    const int rbase = wr * 32;

    {   // aggregation: 4 thr/row x 32 ch; j-unrolled for ILP
        const int r = tid >> 2, sgi = tid & 3;
        const int node = row0 + r;
        const int beg = offsets[node], end = offsets[node + 1];
        float s[32];
        #pragma unroll
        for (int k = 0; k < 32; k++) s[k] = 0.0f;
        const u16* ebase = e + sgi * 32;
        int j = beg;
        for (; j + 2 <= end; j += 2) {
            const bf16x8* e0 = (const bf16x8*)(ebase + (size_t)j * HD);
            const bf16x8* e1 = (const bf16x8*)(ebase + (size_t)(j + 1) * HD);
            bf16x8 v0 = e0[0], v1 = e0[1], v2 = e0[2], v3 = e0[3];
            bf16x8 u0 = e1[0], u1 = e1[1], u2 = e1[2], u3 = e1[3];
            #pragma unroll
            for (int k = 0; k < 8; k++) {
                s[k]      += b2f((u16)v0[k]) + b2f((u16)u0[k]);
                s[8 + k]  += b2f((u16)v1[k]) + b2f((u16)u1[k]);
                s[16 + k] += b2f((u16)v2[k]) + b2f((u16)u2[k]);
                s[24 + k] += b2f((u16)v3[k]) + b2f((u16)u3[k]);
            }
        }
        if (j < end) {
            const bf16x8* e0 = (const bf16x8*)(ebase + (size_t)j * HD);
            bf16x8 v0 = e0[0], v1 = e0[1], v2 = e0[2], v3 = e0[3];
            #pragma unroll
            for (int k = 0; k < 8; k++) {
                s[k]      += b2f((u16)v0[k]);
                s[8 + k]  += b2f((u16)v1[k]);
                s[16 + k] += b2f((u16)v2[k]);
                s[24 + k] += b2f((u16)v3[k]);
            }
        }
        #pragma unroll
        for (int q = 0; q < 4; q++) {
            bf16x8 o;
            #pragma unroll
            for (int k = 0; k < 8; k++) o[k] = (short)f2b(s[q * 8 + k]);
            *(bf16x8*)(aggT + r * 136 + sgi * 32 + q * 8) = o;
        }
    }
    __syncthreads();

    f32x4 acc[2][4];
    zero_accs<2>(acc);
    const u16* b1p = W1f + (size_t)(wc * 32) * 512 + lane * 8;  // KC1=8
    const u16* hp[2];
    #pragma unroll
    for (int g = 0; g < 2; g++)
        hp[g] = h + (size_t)(row0 + rbase + g * 16 + cl) * HD + kl8;
    #pragma unroll
    for (int k0 = 0; k0 < 4; k0++) {   // h section
        bf16x8 b[4];
        #pragma unroll
        for (int ct = 0; ct < 4; ct++) b[ct] = *(const bf16x8*)(b1p + (ct * 8 + k0) * 512);
        #pragma unroll
        for (int g = 0; g < 2; g++) {
            bf16x8 a = *(const bf16x8*)(hp[g] + k0 * 32);
            mfma4g(a, b, acc[g]);
        }
    }
    #pragma unroll
    for (int k0 = 0; k0 < 4; k0++) {   // agg section (LDS)
        bf16x8 b[4];
        #pragma unroll
        for (int ct = 0; ct < 4; ct++) b[ct] = *(const bf16x8*)(b1p + (ct * 8 + 4 + k0) * 512);
        #pragma unroll
        for (int g = 0; g < 2; g++) {
            bf16x8 a = *(const bf16x8*)(aggT + (rbase + g * 16 + cl) * 136 + k0 * 32 + kl8);
            mfma4g(a, b, acc[g]);
        }
    }
    store_tile_rg<2, true>(tb, rbase, wc, lane, acc, b1);
    __syncthreads();
    zero_accs<2>(acc);
    gemm_tb_rg<2>(tb, rbase, W2f, wc, lane, acc);
    __syncthreads();
    store_tile_rg<2, true>(tb, rbase, wc, lane, acc, b2);
    __syncthreads();
    zero_accs<2>(acc);
    gemm_tb_rg<2>(tb, rbase, W3f, wc, lane, acc);
    __syncthreads();
    #pragma unroll
    for (int g = 0; g < 2; g++) {   // residual with old h
        const int r0 = rbase + g * 16 + (lane >> 4) * 4;
        #pragma unroll
        for (int ct = 0; ct < 4; ct++) {
            int col = wc * 64 + ct * 16 + cl;
            float bv = b3[col];
            #pragma unroll
            for (int i = 0; i < 4; i++) {
                float old = b2f(h[(size_t)(row0 + r0 + i) * HD + col]);
                tb[(r0 + i) * 136 + col] = f2b(old + acc[g][ct][i] + bv);
            }
        }
    }
    __syncthreads();
    #pragma unroll
    for (int p = 0; p < 2; p++) {
        const int r = p * 32 + (tid >> 3), sgi = tid & 7;
        const int grow = row0 + r;
        float4* ho = (float4*)(h + (size_t)grow * HD);
        ho[sgi]     = *(const float4*)(tb + r * 136 + sgi * 8);
        ho[8 + sgi] = *(const float4*)(tb + r * 136 + 64 + sgi * 8);
    }
}

// ---------------- decoder: h -> MLP(H,H,OUT=2) fp32 out ----------------
__global__ __launch_bounds__(256, 4) void dec_mfma(
    const u16* __restrict__ h,
    const u16* __restrict__ W1f, const float* __restrict__ b1,
    const u16* __restrict__ W2f, const float* __restrict__ b2,
    const float* __restrict__ W3, const float* __restrict__ b3,
    float* __restrict__ out) {
    __shared__ u16 tb[32 * 136];
    const int tid = threadIdx.x;
    const int lane = tid & 63, w = tid >> 6, wr = w >> 1, wc = w & 1;
    const int cl = lane & 15, kl8 = (lane >> 4) * 8;
    const int row0 = blockIdx.x * 32;
    const int myrow = row0 + wr * 16 + cl;
    const u16* hp = h + (size_t)myrow * HD + kl8;

    f32x4 acc[1][4];
    zero_accs<1>(acc);
    const u16* b1p = W1f + (size_t)(wc * 16) * 512 + lane * 8;
    #pragma unroll
    for (int k0 = 0; k0 < 4; k0++) {
        bf16x8 b[4];
        #pragma unroll
        for (int ct = 0; ct < 4; ct++) b[ct] = *(const bf16x8*)(b1p + (ct * 4 + k0) * 512);
        bf16x8 a = *(const bf16x8*)(hp + k0 * 32);
        mfma4g(a, b, acc[0]);
    }
    store_tile_rg<1, true>(tb, wr * 16, wc, lane, acc, b1);
    __syncthreads();
    zero_accs<1>(acc);
    gemm_tb_rg<1>(tb, wr * 16, W2f, wc, lane, acc);
    __syncthreads();
    store_tile_rg<1, true>(tb, wr * 16, wc, lane, acc, b2);
    __syncthreads();
    if (tid < 64) {
        const int rr = tid >> 1, o = tid & 1;
        const int grow = row0 + rr;
        if (grow < NND) {
            float a = b3[o];
            for (int k = 0; k < HD; k++) a += b2f(tb[rr * 136 + k]) * W3[k * 2 + o];
            out[(size_t)grow * 2 + o] = a;
        }
    }
}

extern "C" void kernel_launch(void* const* d_in, const int* in_sizes, int n_in,
                              void* d_out, int out_size, void* d_ws, size_t ws_size,
                              hipStream_t stream) {
    (void)in_sizes; (void)n_in; (void)out_size; (void)ws_size;
    const float* x    = (const float*)d_in[0];
    const float* eatt = (const float*)d_in[1];
    const int*   eidx = (const int*)d_in[2];
    const float *neW1 = (const float*)d_in[3],  *neb1 = (const float*)d_in[4];
    const float *neW2 = (const float*)d_in[5],  *neb2 = (const float*)d_in[6];
    const float *neW3 = (const float*)d_in[7],  *neb3 = (const float*)d_in[8];
    const float *eeW1 = (const float*)d_in[9],  *eeb1 = (const float*)d_in[10];
    const float *eeW2 = (const float*)d_in[11], *eeb2 = (const float*)d_in[12];
    const float *eeW3 = (const float*)d_in[13], *eeb3 = (const float*)d_in[14];
    const float *peW1 = (const float*)d_in[15], *peb1 = (const float*)d_in[16];
    const float *peW2 = (const float*)d_in[17], *peb2 = (const float*)d_in[18];
    const float *peW3 = (const float*)d_in[19], *peb3 = (const float*)d_in[20];
    const float *pnW1 = (const float*)d_in[21], *pnb1 = (const float*)d_in[22];
    const float *pnW2 = (const float*)d_in[23], *pnb2 = (const float*)d_in[24];
    const float *pnW3 = (const float*)d_in[25], *pnb3 = (const float*)d_in[26];
    const float *ndW1 = (const float*)d_in[27], *ndb1 = (const float*)d_in[28];
    const float *ndW2 = (const float*)d_in[29], *ndb2 = (const float*)d_in[30];
    const float *ndW3 = (const float*)d_in[31], *ndb3 = (const float*)d_in[32];

    char* ws = (char*)d_ws;
    u16*   h       = (u16*)ws;                      // [NNDP][HD] bf16
    u16*   e       = (u16*)(ws + 12812288);         // [NED][HD] bf16 (dst-sorted)
    int*   counts  = (int*)(ws + 115212288);
    int*   cursors = (int*)(ws + 115412480);
    int*   offsets = (int*)(ws + 115612672);        // [NNDP+1]
    int*   perm    = (int*)(ws + 115812880);
    int*   srcp    = (int*)(ws + 117412880);
    int*   dstp    = (int*)(ws + 119012880);
    u16*   wts     = (u16*)(ws + 120612880);

    u16* p = wts;
    u16 *neW1t = p; p += 128 * 32;
    u16 *neW2t = p; p += 128 * 128;
    u16 *neW3t = p; p += 128 * 128;
    u16 *eeW1t = p; p += 128 * 32;
    u16 *eeW2t = p; p += 128 * 128;
    u16 *eeW3t = p; p += 128 * 128;
    u16 *peW1t[NSTEP], *peW2t[NSTEP], *peW3t[NSTEP];
    u16 *pnW1t[NSTEP], *pnW2t[NSTEP], *pnW3t[NSTEP];
    for (int t = 0; t < NSTEP; t++) {
        peW1t[t] = p; p += 128 * 384;
        peW2t[t] = p; p += 128 * 128;
        peW3t[t] = p; p += 128 * 128;
    }
    for (int t = 0; t < NSTEP; t++) {
        pnW1t[t] = p; p += 128 * 256;
        pnW2t[t] = p; p += 128 * 128;
        pnW3t[t] = p; p += 128 * 128;
    }
    u16 *ndW1t = p; p += 128 * 128;
    u16 *ndW2t = p; p += 128 * 128;

    hipMemsetAsync(counts, 0, NNDP * sizeof(int), stream);
    count_kernel<<<(NED + 255) / 256, 256, 0, stream>>>(eidx, counts);
    scan_kernel<<<1, 1024, 0, stream>>>(counts, offsets, cursors);
    fill_kernel<<<(NED + 255) / 256, 256, 0, stream>>>(eidx, cursors, perm, srcp, dstp);

    auto WP = [&](const float* s, u16* d, int K, int Kp) {
        int tot = 128 * Kp;
        wprep_frag<<<(tot + 255) / 256, 256, 0, stream>>>(s, d, K, Kp);
    };
    WP(neW1, neW1t, 4, 32);
    WP(neW2, neW2t, 128, 128);
    WP(neW3, neW3t, 128, 128);
    WP(eeW1, eeW1t, 3, 32);
    WP(eeW2, eeW2t, 128, 128);
    WP(eeW3, eeW3t, 128, 128);
    for (int t = 0; t < NSTEP; t++) {
        WP(peW1 + (size_t)t * 384 * 128, peW1t[t], 384, 384);
        WP(peW2 + (size_t)t * 128 * 128, peW2t[t], 128, 128);
        WP(peW3 + (size_t)t * 128 * 128, peW3t[t], 128, 128);
        WP(pnW1 + (size_t)t * 256 * 128, pnW1t[t], 256, 256);
        WP(pnW2 + (size_t)t * 128 * 128, pnW2t[t], 128, 128);
        WP(pnW3 + (size_t)t * 128 * 128, pnW3t[t], 128, 128);
    }
    WP(ndW1, ndW1t, 128, 128);
    WP(ndW2, ndW2t, 128, 128);

    enc_mfma<<<NNDP / 64, 256, 0, stream>>>(x, 4, NND, nullptr,
                                            neW1t, neb1, neW2t, neb2, neW3t, neb3, h);
    enc_mfma<<<NED / 64, 256, 0, stream>>>(eatt, 3, NED, perm,
                                           eeW1t, eeb1, eeW2t, eeb2, eeW3t, eeb3, e);

    for (int t = 0; t < NSTEP; t++) {
        edge_mfma<<<NED / 128, 256, 0, stream>>>(
            h, e, srcp, dstp,
            peW1t[t], peb1 + (size_t)t * HD,
            peW2t[t], peb2 + (size_t)t * HD,
            peW3t[t], peb3 + (size_t)t * HD);
        node_mfma<<<NNDP / 64, 256, 0, stream>>>(
            h, e, offsets,
            pnW1t[t], pnb1 + (size_t)t * HD,
            pnW2t[t], pnb2 + (size_t)t * HD,
            pnW3t[t], pnb3 + (size_t)t * HD);
    }
    dec_mfma<<<NNDP / 32, 256, 0, stream>>>(h, ndW1t, ndb1, ndW2t, ndb2, ndW3, ndb3, (float*)d_out);
}

// Round 6
// 715.481 us; speedup vs baseline: 19.1645x; 1.2171x over previous
//
#include <hip/hip_runtime.h>
#include <cstddef>

#define NND 50000
#define NNDP 50048   // padded: multiple of 128
#define NED 400000
#define HD 128
#define NSTEP 3
#define SCAN_CHUNK 49  // 1024*49 >= NNDP+1
#define NWP 26

using u16 = unsigned short;
typedef __attribute__((ext_vector_type(8))) short bf16x8;
typedef __attribute__((ext_vector_type(4))) float f32x4;

__device__ __forceinline__ u16 f2b(float f) {
    union { float f; unsigned u; } v; v.f = f;
    unsigned r = v.u + 0x7FFFu + ((v.u >> 16) & 1u);
    return (u16)(r >> 16);
}
__device__ __forceinline__ float b2f(u16 u) {
    union { unsigned u; float f; } v; v.u = ((unsigned)u) << 16;
    return v.f;
}

template <int RG>
__device__ __forceinline__ void zero_accs(f32x4 (&acc)[RG][4]) {
    #pragma unroll
    for (int g = 0; g < RG; g++)
        #pragma unroll
        for (int i = 0; i < 4; i++) acc[g][i] = (f32x4)(0.0f);
}

__device__ __forceinline__ void mfma4g(bf16x8 a, const bf16x8 (&b)[4], f32x4 (&accg)[4]) {
    accg[0] = __builtin_amdgcn_mfma_f32_16x16x32_bf16(a, b[0], accg[0], 0, 0, 0);
    accg[1] = __builtin_amdgcn_mfma_f32_16x16x32_bf16(a, b[1], accg[1], 0, 0, 0);
    accg[2] = __builtin_amdgcn_mfma_f32_16x16x32_bf16(a, b[2], accg[2], 0, 0, 0);
    accg[3] = __builtin_amdgcn_mfma_f32_16x16x32_bf16(a, b[3], accg[3], 0, 0, 0);
}

// K=128 layer, A from LDS buf (stride 136), weights fragment-major KC=4.
template <int RG>
__device__ __forceinline__ void gemm_tb_rg(const u16* buf, int rbase,
                                           const u16* __restrict__ Wf,
                                           int wc, int lane, f32x4 (&acc)[RG][4]) {
    const int cl = lane & 15, kl8 = (lane >> 4) * 8;
    const u16* bp = Wf + (size_t)(wc * 16) * 512 + lane * 8;
    #pragma unroll
    for (int k0 = 0; k0 < 4; k0++) {
        bf16x8 b[4];
        #pragma unroll
        for (int ct = 0; ct < 4; ct++) b[ct] = *(const bf16x8*)(bp + (ct * 4 + k0) * 512);
        #pragma unroll
        for (int g = 0; g < RG; g++) {
            bf16x8 a = *(const bf16x8*)(buf + (rbase + g * 16 + cl) * 136 + k0 * 32 + kl8);
            mfma4g(a, b, acc[g]);
        }
    }
}

// C/D layout (m89-verified): col = lane&15, row = (lane>>4)*4 + reg.
template <int RG, bool RELU>
__device__ __forceinline__ void store_tile_rg(u16* T, int rbase, int wc, int lane,
        const f32x4 (&acc)[RG][4], const float* __restrict__ bias) {
    const int cl = lane & 15;
    #pragma unroll
    for (int g = 0; g < RG; g++) {
        const int r0 = rbase + g * 16 + (lane >> 4) * 4;
        #pragma unroll
        for (int ct = 0; ct < 4; ct++) {
            int col = wc * 64 + ct * 16 + cl;
            float bv = bias[col];
            #pragma unroll
            for (int i = 0; i < 4; i++) {
                float v = acc[g][ct][i] + bv;
                if (RELU) v = fmaxf(v, 0.0f);
                T[(r0 + i) * 136 + col] = f2b(v);
            }
        }
    }
}

// ---------------- CSR build ----------------
__global__ void count_kernel(const int* __restrict__ eidx, int* __restrict__ counts) {
    int i = blockIdx.x * 256 + threadIdx.x;
    if (i < NED) atomicAdd(&counts[eidx[NED + i]], 1);
}

__global__ __launch_bounds__(1024) void scan_kernel(const int* __restrict__ counts,
                                                    int* __restrict__ offsets,
                                                    int* __restrict__ cursors) {
    __shared__ int part[1024];
    const int t = threadIdx.x;
    const int base = t * SCAN_CHUNK;
    int s = 0;
    for (int j = 0; j < SCAN_CHUNK; j++) {
        int idx = base + j;
        if (idx < NNDP) s += counts[idx];
    }
    part[t] = s;
    __syncthreads();
    for (int ofs = 1; ofs < 1024; ofs <<= 1) {
        int v = (t >= ofs) ? part[t - ofs] : 0;
        __syncthreads();
        part[t] += v;
        __syncthreads();
    }
    int run = (t > 0) ? part[t - 1] : 0;
    for (int j = 0; j < SCAN_CHUNK; j++) {
        int idx = base + j;
        if (idx < NNDP) {
            offsets[idx] = run;
            cursors[idx] = run;
            run += counts[idx];
        }
    }
    if (t == 1023) offsets[NNDP] = part[1023];
}

__global__ void fill_kernel(const int* __restrict__ eidx, int* __restrict__ cursors,
                            int* __restrict__ perm, int* __restrict__ srcp,
                            int* __restrict__ dstp) {
    int i = blockIdx.x * 256 + threadIdx.x;
    if (i >= NED) return;
    int d = eidx[NED + i];
    int pos = atomicAdd(&cursors[d], 1);
    perm[pos] = i;
    srcp[pos] = eidx[i];
    dstp[pos] = d;
}

// ---------------- fused weight prep: 26 weights in ONE kernel ----------------
struct WPall {
    const float* s[NWP];
    u16* d[NWP];
    int K[NWP];
    int Kp[NWP];
};

__global__ void wprep_all(WPall a) {
    const int wi = blockIdx.y;
    const int Kp = a.Kp[wi];
    int idx = blockIdx.x * 256 + threadIdx.x;
    if (idx >= 128 * Kp) return;
    const int K = a.K[wi];
    const float* __restrict__ src = a.s[wi];
    int j = idx & 7, lane = (idx >> 3) & 63, rest = idx >> 9;
    int KC = Kp >> 5;
    int k0 = rest % KC, n0 = rest / KC;
    int n = n0 * 16 + (lane & 15);
    int k = k0 * 32 + (lane >> 4) * 8 + j;
    float v = (k < K) ? src[(size_t)k * 128 + n] : 0.0f;
    a.d[wi][idx] = f2b(v);
}

// ---------------- encoder (BM=64, RG=2), ping-pong t1/t2, 3 barriers ----------------
__global__ __launch_bounds__(256, 4) void enc_mfma(
    const float* __restrict__ in, int Kin, int nrows, const int* __restrict__ perm,
    const u16* __restrict__ W1f, const float* __restrict__ b1,
    const u16* __restrict__ W2f, const float* __restrict__ b2,
    const u16* __restrict__ W3f, const float* __restrict__ b3,
    u16* __restrict__ out) {
    __shared__ u16 t1[64 * 136];
    __shared__ u16 t2[64 * 136];
    const int tid = threadIdx.x;
    const int lane = tid & 63, w = tid >> 6, wr = w >> 1, wc = w & 1;
    const int cl = lane & 15, kl8 = (lane >> 4) * 8;
    const int row0 = blockIdx.x * 64;
    const int rbase = wr * 32;

    f32x4 acc[2][4];
    zero_accs<2>(acc);
    bf16x8 a[2];
    #pragma unroll
    for (int g = 0; g < 2; g++) {
        a[g] = (bf16x8){0, 0, 0, 0, 0, 0, 0, 0};
        int grow = row0 + rbase + g * 16 + cl;
        if (kl8 == 0 && grow < nrows) {
            int irow = perm ? perm[grow] : grow;
            const float* xr = in + (size_t)irow * Kin;
            if (Kin == 4) {
                float4 v = *(const float4*)xr;
                a[g][0] = (short)f2b(v.x); a[g][1] = (short)f2b(v.y);
                a[g][2] = (short)f2b(v.z); a[g][3] = (short)f2b(v.w);
            } else {
                a[g][0] = (short)f2b(xr[0]); a[g][1] = (short)f2b(xr[1]);
                a[g][2] = (short)f2b(xr[2]);
            }
        }
    }
    {
        const u16* b1p = W1f + (size_t)(wc * 4) * 512 + lane * 8;  // KC=1
        bf16x8 b[4];
        #pragma unroll
        for (int ct = 0; ct < 4; ct++) b[ct] = *(const bf16x8*)(b1p + ct * 512);
        #pragma unroll
        for (int g = 0; g < 2; g++) mfma4g(a[g], b, acc[g]);
    }
    store_tile_rg<2, true>(t1, rbase, wc, lane, acc, b1);
    __syncthreads();
    zero_accs<2>(acc);
    gemm_tb_rg<2>(t1, rbase, W2f, wc, lane, acc);
    store_tile_rg<2, true>(t2, rbase, wc, lane, acc, b2);
    __syncthreads();
    zero_accs<2>(acc);
    gemm_tb_rg<2>(t2, rbase, W3f, wc, lane, acc);
    store_tile_rg<2, false>(t1, rbase, wc, lane, acc, b3);
    __syncthreads();
    #pragma unroll
    for (int p = 0; p < 2; p++) {
        const int r = p * 32 + (tid >> 3), sgi = tid & 7;
        const int orow = row0 + r;
        if (orow < nrows) {
            float4* dst = (float4*)(out + (size_t)orow * HD);
            dst[sgi]     = *(const float4*)(t1 + r * 136 + sgi * 8);
            dst[8 + sgi] = *(const float4*)(t1 + r * 136 + 64 + sgi * 8);
        }
    }
}

// ---------------- edge step (BM=128, RG=4): 3 barriers, residual folded in final store ----------------
__global__ __launch_bounds__(256, 2) void edge_mfma(
    const u16* __restrict__ h, u16* __restrict__ e,
    const int* __restrict__ srcp, const int* __restrict__ dstp,
    const u16* __restrict__ W1f, const float* __restrict__ b1,
    const u16* __restrict__ W2f, const float* __restrict__ b2,
    const u16* __restrict__ W3f, const float* __restrict__ b3) {
    __shared__ u16 t1[128 * 136];
    __shared__ u16 t2[128 * 136];
    const int tid = threadIdx.x;
    const int lane = tid & 63, w = tid >> 6, wr = w >> 1, wc = w & 1;
    const int cl = lane & 15, kl8 = (lane >> 4) * 8;
    const int row0 = blockIdx.x * 128;
    const int rbase = wr * 64;

    const u16 *hsv[4], *hdv[4], *epv[4];
    #pragma unroll
    for (int g = 0; g < 4; g++) {
        int myrow = row0 + rbase + g * 16 + cl;
        hsv[g] = h + (size_t)srcp[myrow] * HD + kl8;
        hdv[g] = h + (size_t)dstp[myrow] * HD + kl8;
        epv[g] = e + (size_t)myrow * HD + kl8;
    }

    f32x4 acc[4][4];
    zero_accs<4>(acc);
    const u16* b1p = W1f + (size_t)(wc * 48) * 512 + lane * 8;  // KC1=12
    #pragma unroll
    for (int k0 = 0; k0 < 4; k0++) {   // h[src] section
        bf16x8 b[4];
        #pragma unroll
        for (int ct = 0; ct < 4; ct++) b[ct] = *(const bf16x8*)(b1p + (ct * 12 + k0) * 512);
        #pragma unroll
        for (int g = 0; g < 4; g++) {
            bf16x8 a = *(const bf16x8*)(hsv[g] + k0 * 32);
            mfma4g(a, b, acc[g]);
        }
    }
    #pragma unroll
    for (int k0 = 0; k0 < 4; k0++) {   // h[dst] section
        bf16x8 b[4];
        #pragma unroll
        for (int ct = 0; ct < 4; ct++) b[ct] = *(const bf16x8*)(b1p + (ct * 12 + 4 + k0) * 512);
        #pragma unroll
        for (int g = 0; g < 4; g++) {
            bf16x8 a = *(const bf16x8*)(hdv[g] + k0 * 32);
            mfma4g(a, b, acc[g]);
        }
    }
    #pragma unroll
    for (int k0 = 0; k0 < 4; k0++) {   // e section
        bf16x8 b[4];
        #pragma unroll
        for (int ct = 0; ct < 4; ct++) b[ct] = *(const bf16x8*)(b1p + (ct * 12 + 8 + k0) * 512);
        #pragma unroll
        for (int g = 0; g < 4; g++) {
            bf16x8 a = *(const bf16x8*)(epv[g] + k0 * 32);
            mfma4g(a, b, acc[g]);
        }
    }
    store_tile_rg<4, true>(t1, rbase, wc, lane, acc, b1);
    __syncthreads();
    zero_accs<4>(acc);
    gemm_tb_rg<4>(t1, rbase, W2f, wc, lane, acc);
    store_tile_rg<4, true>(t2, rbase, wc, lane, acc, b2);
    __syncthreads();
    zero_accs<4>(acc);
    gemm_tb_rg<4>(t2, rbase, W3f, wc, lane, acc);
    store_tile_rg<4, false>(t1, rbase, wc, lane, acc, b3);
    __syncthreads();
    // final: residual (old e, coalesced) + store
    #pragma unroll
    for (int p = 0; p < 4; p++) {
        const int r = p * 32 + (tid >> 3), sgi = tid & 7;
        const int grow = row0 + r;
        u16* erow = e + (size_t)grow * HD;
        #pragma unroll
        for (int half = 0; half < 2; half++) {
            bf16x8 tv = *(const bf16x8*)(t1 + r * 136 + half * 64 + sgi * 8);
            bf16x8 ov = *(const bf16x8*)(erow + half * 64 + sgi * 8);
            bf16x8 res;
            #pragma unroll
            for (int k = 0; k < 8; k++)
                res[k] = (short)f2b(b2f((u16)tv[k]) + b2f((u16)ov[k]));
            *(bf16x8*)(erow + half * 64 + sgi * 8) = res;
        }
    }
}

// ---------------- node step (BM=64, RG=2): aggT dual-used as ping-pong, 4 barriers ----------------
__global__ __launch_bounds__(256, 3) void node_mfma(
    u16* __restrict__ h, const u16* __restrict__ e, const int* __restrict__ offsets,
    const u16* __restrict__ W1f, const float* __restrict__ b1,
    const u16* __restrict__ W2f, const float* __restrict__ b2,
    const u16* __restrict__ W3f, const float* __restrict__ b3) {
    __shared__ u16 tb[64 * 136];
    __shared__ u16 aggT[64 * 136];
    const int tid = threadIdx.x;
    const int lane = tid & 63, w = tid >> 6, wr = w >> 1, wc = w & 1;
    const int cl = lane & 15, kl8 = (lane >> 4) * 8;
    const int row0 = blockIdx.x * 64;
    const int rbase = wr * 32;

    {   // aggregation: 4 thr/row x 32 ch; j-unrolled for ILP
        const int r = tid >> 2, sgi = tid & 3;
        const int node = row0 + r;
        const int beg = offsets[node], end = offsets[node + 1];
        float s[32];
        #pragma unroll
        for (int k = 0; k < 32; k++) s[k] = 0.0f;
        const u16* ebase = e + sgi * 32;
        int j = beg;
        for (; j + 2 <= end; j += 2) {
            const bf16x8* e0 = (const bf16x8*)(ebase + (size_t)j * HD);
            const bf16x8* e1 = (const bf16x8*)(ebase + (size_t)(j + 1) * HD);
            bf16x8 v0 = e0[0], v1 = e0[1], v2 = e0[2], v3 = e0[3];
            bf16x8 u0 = e1[0], u1 = e1[1], u2 = e1[2], u3 = e1[3];
            #pragma unroll
            for (int k = 0; k < 8; k++) {
                s[k]      += b2f((u16)v0[k]) + b2f((u16)u0[k]);
                s[8 + k]  += b2f((u16)v1[k]) + b2f((u16)u1[k]);
                s[16 + k] += b2f((u16)v2[k]) + b2f((u16)u2[k]);
                s[24 + k] += b2f((u16)v3[k]) + b2f((u16)u3[k]);
            }
        }
        if (j < end) {
            const bf16x8* e0 = (const bf16x8*)(ebase + (size_t)j * HD);
            bf16x8 v0 = e0[0], v1 = e0[1], v2 = e0[2], v3 = e0[3];
            #pragma unroll
            for (int k = 0; k < 8; k++) {
                s[k]      += b2f((u16)v0[k]);
                s[8 + k]  += b2f((u16)v1[k]);
                s[16 + k] += b2f((u16)v2[k]);
                s[24 + k] += b2f((u16)v3[k]);
            }
        }
        #pragma unroll
        for (int q = 0; q < 4; q++) {
            bf16x8 o;
            #pragma unroll
            for (int k = 0; k < 8; k++) o[k] = (short)f2b(s[q * 8 + k]);
            *(bf16x8*)(aggT + r * 136 + sgi * 32 + q * 8) = o;
        }
    }
    __syncthreads();

    f32x4 acc[2][4];
    zero_accs<2>(acc);
    const u16* b1p = W1f + (size_t)(wc * 32) * 512 + lane * 8;  // KC1=8
    const u16* hp[2];
    #pragma unroll
    for (int g = 0; g < 2; g++)
        hp[g] = h + (size_t)(row0 + rbase + g * 16 + cl) * HD + kl8;
    #pragma unroll
    for (int k0 = 0; k0 < 4; k0++) {   // h section (coalesced rows)
        bf16x8 b[4];
        #pragma unroll
        for (int ct = 0; ct < 4; ct++) b[ct] = *(const bf16x8*)(b1p + (ct * 8 + k0) * 512);
        #pragma unroll
        for (int g = 0; g < 2; g++) {
            bf16x8 a = *(const bf16x8*)(hp[g] + k0 * 32);
            mfma4g(a, b, acc[g]);
        }
    }
    #pragma unroll
    for (int k0 = 0; k0 < 4; k0++) {   // agg section (LDS)
        bf16x8 b[4];
        #pragma unroll
        for (int ct = 0; ct < 4; ct++) b[ct] = *(const bf16x8*)(b1p + (ct * 8 + 4 + k0) * 512);
        #pragma unroll
        for (int g = 0; g < 2; g++) {
            bf16x8 a = *(const bf16x8*)(aggT + (rbase + g * 16 + cl) * 136 + k0 * 32 + kl8);
            mfma4g(a, b, acc[g]);
        }
    }
    store_tile_rg<2, true>(tb, rbase, wc, lane, acc, b1);
    __syncthreads();
    zero_accs<2>(acc);
    gemm_tb_rg<2>(tb, rbase, W2f, wc, lane, acc);
    store_tile_rg<2, true>(aggT, rbase, wc, lane, acc, b2);
    __syncthreads();
    zero_accs<2>(acc);
    gemm_tb_rg<2>(aggT, rbase, W3f, wc, lane, acc);
    store_tile_rg<2, false>(tb, rbase, wc, lane, acc, b3);
    __syncthreads();
    // final: residual (old h, coalesced) + store
    #pragma unroll
    for (int p = 0; p < 2; p++) {
        const int r = p * 32 + (tid >> 3), sgi = tid & 7;
        const int grow = row0 + r;
        u16* hrow = h + (size_t)grow * HD;
        #pragma unroll
        for (int half = 0; half < 2; half++) {
            bf16x8 tv = *(const bf16x8*)(tb + r * 136 + half * 64 + sgi * 8);
            bf16x8 ov = *(const bf16x8*)(hrow + half * 64 + sgi * 8);
            bf16x8 res;
            #pragma unroll
            for (int k = 0; k < 8; k++)
                res[k] = (short)f2b(b2f((u16)tv[k]) + b2f((u16)ov[k]));
            *(bf16x8*)(hrow + half * 64 + sgi * 8) = res;
        }
    }
}

// ---------------- decoder: h -> MLP(H,H,OUT=2) fp32 out ----------------
__global__ __launch_bounds__(256, 4) void dec_mfma(
    const u16* __restrict__ h,
    const u16* __restrict__ W1f, const float* __restrict__ b1,
    const u16* __restrict__ W2f, const float* __restrict__ b2,
    const float* __restrict__ W3, const float* __restrict__ b3,
    float* __restrict__ out) {
    __shared__ u16 t1[32 * 136];
    __shared__ u16 t2[32 * 136];
    const int tid = threadIdx.x;
    const int lane = tid & 63, w = tid >> 6, wr = w >> 1, wc = w & 1;
    const int cl = lane & 15, kl8 = (lane >> 4) * 8;
    const int row0 = blockIdx.x * 32;
    const int myrow = row0 + wr * 16 + cl;
    const u16* hp = h + (size_t)myrow * HD + kl8;

    f32x4 acc[1][4];
    zero_accs<1>(acc);
    const u16* b1p = W1f + (size_t)(wc * 16) * 512 + lane * 8;
    #pragma unroll
    for (int k0 = 0; k0 < 4; k0++) {
        bf16x8 b[4];
        #pragma unroll
        for (int ct = 0; ct < 4; ct++) b[ct] = *(const bf16x8*)(b1p + (ct * 4 + k0) * 512);
        bf16x8 a = *(const bf16x8*)(hp + k0 * 32);
        mfma4g(a, b, acc[0]);
    }
    store_tile_rg<1, true>(t1, wr * 16, wc, lane, acc, b1);
    __syncthreads();
    zero_accs<1>(acc);
    gemm_tb_rg<1>(t1, wr * 16, W2f, wc, lane, acc);
    store_tile_rg<1, true>(t2, wr * 16, wc, lane, acc, b2);
    __syncthreads();
    if (tid < 64) {
        const int rr = tid >> 1, o = tid & 1;
        const int grow = row0 + rr;
        if (grow < NND) {
            float a = b3[o];
            for (int k = 0; k < HD; k++) a += b2f(t2[rr * 136 + k]) * W3[k * 2 + o];
            out[(size_t)grow * 2 + o] = a;
        }
    }
}

extern "C" void kernel_launch(void* const* d_in, const int* in_sizes, int n_in,
                              void* d_out, int out_size, void* d_ws, size_t ws_size,
                              hipStream_t stream) {
    (void)in_sizes; (void)n_in; (void)out_size; (void)ws_size;
    const float* x    = (const float*)d_in[0];
    const float* eatt = (const float*)d_in[1];
    const int*   eidx = (const int*)d_in[2];
    const float *neW1 = (const float*)d_in[3],  *neb1 = (const float*)d_in[4];
    const float *neW2 = (const float*)d_in[5],  *neb2 = (const float*)d_in[6];
    const float *neW3 = (const float*)d_in[7],  *neb3 = (const float*)d_in[8];
    const float *eeW1 = (const float*)d_in[9],  *eeb1 = (const float*)d_in[10];
    const float *eeW2 = (const float*)d_in[11], *eeb2 = (const float*)d_in[12];
    const float *eeW3 = (const float*)d_in[13], *eeb3 = (const float*)d_in[14];
    const float *peW1 = (const float*)d_in[15], *peb1 = (const float*)d_in[16];
    const float *peW2 = (const float*)d_in[17], *peb2 = (const float*)d_in[18];
    const float *peW3 = (const float*)d_in[19], *peb3 = (const float*)d_in[20];
    const float *pnW1 = (const float*)d_in[21], *pnb1 = (const float*)d_in[22];
    const float *pnW2 = (const float*)d_in[23], *pnb2 = (const float*)d_in[24];
    const float *pnW3 = (const float*)d_in[25], *pnb3 = (const float*)d_in[26];
    const float *ndW1 = (const float*)d_in[27], *ndb1 = (const float*)d_in[28];
    const float *ndW2 = (const float*)d_in[29], *ndb2 = (const float*)d_in[30];
    const float *ndW3 = (const float*)d_in[31], *ndb3 = (const float*)d_in[32];

    char* ws = (char*)d_ws;
    u16*   h       = (u16*)ws;                      // [NNDP][HD] bf16
    u16*   e       = (u16*)(ws + 12812288);         // [NED][HD] bf16 (dst-sorted)
    int*   counts  = (int*)(ws + 115212288);
    int*   cursors = (int*)(ws + 115412480);
    int*   offsets = (int*)(ws + 115612672);        // [NNDP+1]
    int*   perm    = (int*)(ws + 115812880);
    int*   srcp    = (int*)(ws + 117412880);
    int*   dstp    = (int*)(ws + 119012880);
    u16*   wts     = (u16*)(ws + 120612880);

    u16* p = wts;
    u16 *neW1t = p; p += 128 * 32;
    u16 *neW2t = p; p += 128 * 128;
    u16 *neW3t = p; p += 128 * 128;
    u16 *eeW1t = p; p += 128 * 32;
    u16 *eeW2t = p; p += 128 * 128;
    u16 *eeW3t = p; p += 128 * 128;
    u16 *peW1t[NSTEP], *peW2t[NSTEP], *peW3t[NSTEP];
    u16 *pnW1t[NSTEP], *pnW2t[NSTEP], *pnW3t[NSTEP];
    for (int t = 0; t < NSTEP; t++) {
        peW1t[t] = p; p += 128 * 384;
        peW2t[t] = p; p += 128 * 128;
        peW3t[t] = p; p += 128 * 128;
    }
    for (int t = 0; t < NSTEP; t++) {
        pnW1t[t] = p; p += 128 * 256;
        pnW2t[t] = p; p += 128 * 128;
        pnW3t[t] = p; p += 128 * 128;
    }
    u16 *ndW1t = p; p += 128 * 128;
    u16 *ndW2t = p; p += 128 * 128;

    hipMemsetAsync(counts, 0, NNDP * sizeof(int), stream);
    count_kernel<<<(NED + 255) / 256, 256, 0, stream>>>(eidx, counts);
    scan_kernel<<<1, 1024, 0, stream>>>(counts, offsets, cursors);
    fill_kernel<<<(NED + 255) / 256, 256, 0, stream>>>(eidx, cursors, perm, srcp, dstp);

    // fused weight prep: one kernel for all 26 weight tensors
    WPall wa;
    int wn = 0;
    auto ADD = [&](const float* s, u16* d, int K, int Kp) {
        wa.s[wn] = s; wa.d[wn] = d; wa.K[wn] = K; wa.Kp[wn] = Kp; wn++;
    };
    ADD(neW1, neW1t, 4, 32);
    ADD(neW2, neW2t, 128, 128);
    ADD(neW3, neW3t, 128, 128);
    ADD(eeW1, eeW1t, 3, 32);
    ADD(eeW2, eeW2t, 128, 128);
    ADD(eeW3, eeW3t, 128, 128);
    for (int t = 0; t < NSTEP; t++) {
        ADD(peW1 + (size_t)t * 384 * 128, peW1t[t], 384, 384);
        ADD(peW2 + (size_t)t * 128 * 128, peW2t[t], 128, 128);
        ADD(peW3 + (size_t)t * 128 * 128, peW3t[t], 128, 128);
        ADD(pnW1 + (size_t)t * 256 * 128, pnW1t[t], 256, 256);
        ADD(pnW2 + (size_t)t * 128 * 128, pnW2t[t], 128, 128);
        ADD(pnW3 + (size_t)t * 128 * 128, pnW3t[t], 128, 128);
    }
    ADD(ndW1, ndW1t, 128, 128);
    ADD(ndW2, ndW2t, 128, 128);
    wprep_all<<<dim3(192, NWP), 256, 0, stream>>>(wa);

    enc_mfma<<<NNDP / 64, 256, 0, stream>>>(x, 4, NND, nullptr,
                                            neW1t, neb1, neW2t, neb2, neW3t, neb3, h);
    enc_mfma<<<NED / 64, 256, 0, stream>>>(eatt, 3, NED, perm,
                                           eeW1t, eeb1, eeW2t, eeb2, eeW3t, eeb3, e);

    for (int t = 0; t < NSTEP; t++) {
        edge_mfma<<<NED / 128, 256, 0, stream>>>(
            h, e, srcp, dstp,
            peW1t[t], peb1 + (size_t)t * HD,
            peW2t[t], peb2 + (size_t)t * HD,
            peW3t[t], peb3 + (size_t)t * HD);
        node_mfma<<<NNDP / 64, 256, 0, stream>>>(
            h, e, offsets,
            pnW1t[t], pnb1 + (size_t)t * HD,
            pnW2t[t], pnb2 + (size_t)t * HD,
            pnW3t[t], pnb3 + (size_t)t * HD);
    }
    dec_mfma<<<NNDP / 32, 256, 0, stream>>>(h, ndW1t, ndb1, ndW2t, ndb2, ndW3, ndb3, (float*)d_out);
}